// Round 17
// baseline (232.077 us; speedup 1.0000x reference)
//
#include <hip/hip_runtime.h>
#include <cstddef>

typedef __attribute__((ext_vector_type(8))) short short8;
typedef __attribute__((ext_vector_type(4))) float f4;
typedef __attribute__((ext_vector_type(4))) unsigned int u4;

__device__ __forceinline__ unsigned int f2bf(float f){
  unsigned int u = __float_as_uint(f);
  u += 0x7fffu + ((u >> 16) & 1u);   // RNE to bf16
  return u >> 16;
}
__device__ __forceinline__ float bflo(unsigned int w){ return __uint_as_float((w & 0xFFFFu) << 16); }
__device__ __forceinline__ float bfhi(unsigned int w){ return __uint_as_float(w & 0xFFFF0000u); }
__device__ __forceinline__ float fsign(float x){ return (x > 0.f) ? 1.f : ((x < 0.f) ? -1.f : 0.f); }
__device__ __forceinline__ float hclip(float x){ return fminf(1.f, fmaxf(-1.f, x)); }

#define SB0 __builtin_amdgcn_sched_barrier(0)

// lgkm-only barrier (used by gemm2 only)
#define BARRIER() do { \
    SB0; \
    asm volatile("s_waitcnt lgkmcnt(0)" ::: "memory"); \
    __builtin_amdgcn_s_barrier(); \
    asm volatile("" ::: "memory"); \
    SB0; \
  } while(0)

// ---------------- prep: sign weights -> bf16 {+1,-1,0} ----------------------------------------
// W1 -> FRAGMENT-MAJOR W'[k>>5][n][(k>>3)&3][k&7]: wave B-frag load = 1KB contiguous.
// W2 -> row-major (gemm2 unchanged).
__global__ void prep_sign_k(const float* __restrict__ W1, unsigned short* __restrict__ w1f,
                            const float* __restrict__ W2, unsigned short* __restrict__ w2s){
  int i = (blockIdx.x * blockDim.x + threadIdx.x) * 8;
  if (i < 1048576){
    int n = i >> 12, k = i & 4095;
    f4 a = *(const f4*)(W1 + i);
    f4 b = *(const f4*)(W1 + i + 4);
    u4 v;
    v.x = (unsigned)((a[0] > 0.f) ? 0x3F80u : (a[0] < 0.f ? 0xBF80u : 0u))
        | ((unsigned)((a[1] > 0.f) ? 0x3F80u : (a[1] < 0.f ? 0xBF80u : 0u)) << 16);
    v.y = (unsigned)((a[2] > 0.f) ? 0x3F80u : (a[2] < 0.f ? 0xBF80u : 0u))
        | ((unsigned)((a[3] > 0.f) ? 0x3F80u : (a[3] < 0.f ? 0xBF80u : 0u)) << 16);
    v.z = (unsigned)((b[0] > 0.f) ? 0x3F80u : (b[0] < 0.f ? 0xBF80u : 0u))
        | ((unsigned)((b[1] > 0.f) ? 0x3F80u : (b[1] < 0.f ? 0xBF80u : 0u)) << 16);
    v.w = (unsigned)((b[2] > 0.f) ? 0x3F80u : (b[2] < 0.f ? 0xBF80u : 0u))
        | ((unsigned)((b[3] > 0.f) ? 0x3F80u : (b[3] < 0.f ? 0xBF80u : 0u)) << 16);
    size_t ob = ((size_t)(k >> 5) * 256 + (size_t)n) * 64 + (size_t)((k >> 3) & 3) * 16;
    *(u4*)((char*)w1f + ob) = v;
  } else {
    int off = i - 1048576;
    if (off >= 32768) return;
    f4 a = *(const f4*)(W2 + off);
    f4 b = *(const f4*)(W2 + off + 4);
    u4 v;
    v.x = (unsigned)((a[0] > 0.f) ? 0x3F80u : (a[0] < 0.f ? 0xBF80u : 0u))
        | ((unsigned)((a[1] > 0.f) ? 0x3F80u : (a[1] < 0.f ? 0xBF80u : 0u)) << 16);
    v.y = (unsigned)((a[2] > 0.f) ? 0x3F80u : (a[2] < 0.f ? 0xBF80u : 0u))
        | ((unsigned)((a[3] > 0.f) ? 0x3F80u : (a[3] < 0.f ? 0xBF80u : 0u)) << 16);
    v.z = (unsigned)((b[0] > 0.f) ? 0x3F80u : (b[0] < 0.f ? 0xBF80u : 0u))
        | ((unsigned)((b[1] > 0.f) ? 0x3F80u : (b[1] < 0.f ? 0xBF80u : 0u)) << 16);
    v.w = (unsigned)((b[2] > 0.f) ? 0x3F80u : (b[2] < 0.f ? 0xBF80u : 0u))
        | ((unsigned)((b[3] > 0.f) ? 0x3F80u : (b[3] < 0.f ? 0xBF80u : 0u)) << 16);
    *(u4*)(w2s + off) = v;
  }
}

// ---------------- GEMM1: ZERO-LDS, ZERO-BARRIER warp-streaming -------------------------------
// BM=64, BN=256, BK=64, 64 steps. 512 thr = 8 independent waves (2 wm x 4 wn), tile 32x64.
// NO shared state, NO s_barrier in the K-loop: each wave self-paces on its own vmem queue.
// A: direct global->reg fp32 (double-buffered sets, issue k+3, convert k+1 -> ~2-step HBM
//    slack), f2bf in-register. Intra-block 4x A duplication absorbed by L1/L2.
// B: frag-major direct global->reg (1KB contiguous, L2-hot), single set, 1-step slack.
__global__ __launch_bounds__(512, 2) void gemm1_k(
    const float* __restrict__ x, const unsigned short* __restrict__ w1f,
    const float* __restrict__ b1, unsigned short* __restrict__ h1,
    float* __restrict__ part1s, float* __restrict__ part1q)
{
  const int tid  = threadIdx.x;
  const int lane = tid & 63;
  const int wid  = tid >> 6;
  const int wm   = wid >> 2;          // 0..1 -> rows wm*32..+31
  const int wn   = wid & 3;           // 0..3 -> cols wn*64..+63
  const int cl   = lane & 15;
  const int g    = lane >> 4;         // 0..3
  const int row0 = blockIdx.x * 64;

  // A per-frag row bases (fm in {0,1}); per-step byte offset = k*256 (+ks*128 +16 halves)
  const char* xr0 = (const char*)(x + (size_t)(row0 + wm * 32 +  0 + cl) * 4096) + g * 32;
  const char* xr1 = (const char*)(x + (size_t)(row0 + wm * 32 + 16 + cl) * 4096) + g * 32;

  // B frag bases: addr = k*32768 + ks*16384 + (wn*64+fn*16+cl)*64 + g*16
  const char* w1p = (const char*)w1f;
  const int bof0 = (wn * 64 +  0 + cl) * 64 + g * 16;
  const int bof1 = (wn * 64 + 16 + cl) * 64 + g * 16;
  const int bof2 = (wn * 64 + 32 + cl) * 64 + g * 16;
  const int bof3 = (wn * 64 + 48 + cl) * 64 + g * 16;

  f4 acc[2][4];
  const f4 z = {0.f, 0.f, 0.f, 0.f};
  #pragma unroll
  for (int i = 0; i < 2; i++)
    #pragma unroll
    for (int j = 0; j < 4; j++) acc[i][j] = z;

  // A raw double-buffer: set P in {0,1}, frags (fm,ks), halves a/b
  f4 r0_00a, r0_00b, r0_01a, r0_01b, r0_10a, r0_10b, r0_11a, r0_11b;
  f4 r1_00a, r1_00b, r1_01a, r1_01b, r1_10a, r1_10b, r1_11a, r1_11b;
  short8 a00, a01, a10, a11;          // converted bf16 A frags
  short8 b00, b01, b10, b11, b20, b21, b30, b31;   // B frags [fn][ks]

#define ISSUEA(P, K) do { \
    size_t _o = (size_t)(K) * 256; \
    r##P##_00a = *(const f4*)(xr0 + _o);       r##P##_00b = *(const f4*)(xr0 + _o + 16); \
    r##P##_01a = *(const f4*)(xr0 + _o + 128); r##P##_01b = *(const f4*)(xr0 + _o + 144); \
    r##P##_10a = *(const f4*)(xr1 + _o);       r##P##_10b = *(const f4*)(xr1 + _o + 16); \
    r##P##_11a = *(const f4*)(xr1 + _o + 128); r##P##_11b = *(const f4*)(xr1 + _o + 144); \
  } while(0)

#define ISSUEB(K) do { \
    const char* _p = w1p + (size_t)(K) * 32768; \
    b00 = *(const short8*)(_p +         bof0);  b01 = *(const short8*)(_p + 16384 + bof0); \
    b10 = *(const short8*)(_p +         bof1);  b11 = *(const short8*)(_p + 16384 + bof1); \
    b20 = *(const short8*)(_p +         bof2);  b21 = *(const short8*)(_p + 16384 + bof2); \
    b30 = *(const short8*)(_p +         bof3);  b31 = *(const short8*)(_p + 16384 + bof3); \
  } while(0)

#define CVT1(DST, RA, RB) do { \
    u4 _pk; \
    _pk.x = f2bf(RA[0]) | (f2bf(RA[1]) << 16); \
    _pk.y = f2bf(RA[2]) | (f2bf(RA[3]) << 16); \
    _pk.z = f2bf(RB[0]) | (f2bf(RB[1]) << 16); \
    _pk.w = f2bf(RB[2]) | (f2bf(RB[3]) << 16); \
    DST = *(short8*)&_pk; \
  } while(0)

#define CONVA(P) do { \
    CVT1(a00, r##P##_00a, r##P##_00b); \
    CVT1(a01, r##P##_01a, r##P##_01b); \
    CVT1(a10, r##P##_10a, r##P##_10b); \
    CVT1(a11, r##P##_11a, r##P##_11b); \
  } while(0)

#define MFMA16() do { \
    __builtin_amdgcn_s_setprio(1); \
    acc[0][0] = __builtin_amdgcn_mfma_f32_16x16x32_bf16(a00, b00, acc[0][0], 0, 0, 0); \
    acc[0][1] = __builtin_amdgcn_mfma_f32_16x16x32_bf16(a00, b10, acc[0][1], 0, 0, 0); \
    acc[0][2] = __builtin_amdgcn_mfma_f32_16x16x32_bf16(a00, b20, acc[0][2], 0, 0, 0); \
    acc[0][3] = __builtin_amdgcn_mfma_f32_16x16x32_bf16(a00, b30, acc[0][3], 0, 0, 0); \
    acc[1][0] = __builtin_amdgcn_mfma_f32_16x16x32_bf16(a10, b00, acc[1][0], 0, 0, 0); \
    acc[1][1] = __builtin_amdgcn_mfma_f32_16x16x32_bf16(a10, b10, acc[1][1], 0, 0, 0); \
    acc[1][2] = __builtin_amdgcn_mfma_f32_16x16x32_bf16(a10, b20, acc[1][2], 0, 0, 0); \
    acc[1][3] = __builtin_amdgcn_mfma_f32_16x16x32_bf16(a10, b30, acc[1][3], 0, 0, 0); \
    acc[0][0] = __builtin_amdgcn_mfma_f32_16x16x32_bf16(a01, b01, acc[0][0], 0, 0, 0); \
    acc[0][1] = __builtin_amdgcn_mfma_f32_16x16x32_bf16(a01, b11, acc[0][1], 0, 0, 0); \
    acc[0][2] = __builtin_amdgcn_mfma_f32_16x16x32_bf16(a01, b21, acc[0][2], 0, 0, 0); \
    acc[0][3] = __builtin_amdgcn_mfma_f32_16x16x32_bf16(a01, b31, acc[0][3], 0, 0, 0); \
    acc[1][0] = __builtin_amdgcn_mfma_f32_16x16x32_bf16(a11, b01, acc[1][0], 0, 0, 0); \
    acc[1][1] = __builtin_amdgcn_mfma_f32_16x16x32_bf16(a11, b11, acc[1][1], 0, 0, 0); \
    acc[1][2] = __builtin_amdgcn_mfma_f32_16x16x32_bf16(a11, b21, acc[1][2], 0, 0, 0); \
    acc[1][3] = __builtin_amdgcn_mfma_f32_16x16x32_bf16(a11, b31, acc[1][3], 0, 0, 0); \
    __builtin_amdgcn_s_setprio(0); \
  } while(0)

// step K (uses Abf16(K) converted last step, B(K) issued last step):
// MFMA(K); issue B(K+1); convert Araw(K+1) (in set P1, issued 2 steps ago); issue Araw(K+3)->P1.
#define STEP(K, P1) do { \
    MFMA16(); \
    SB0; \
    ISSUEB(((K) + 1 < 64) ? (K) + 1 : 63); \
    SB0; \
    CONVA(P1); \
    SB0; \
    ISSUEA(P1, ((K) + 3 < 64) ? (K) + 3 : 63); \
    SB0; \
  } while(0)

  // prologue: Araw(0)->set0 (oldest), B(0); convert A(0); Araw(1)->set1, Araw(2)->set0
  ISSUEA(0, 0);
  ISSUEB(0);
  SB0;
  CONVA(0);          // waits Araw(0) only (oldest in queue); B(0) stays in flight
  ISSUEA(1, 1);
  ISSUEA(0, 2);
  SB0;

  // even k: convert set1 (holds Araw(k+1)); odd k: convert set0 — literal set indices
  for (int k = 0; k < 64; k += 2){
    STEP(k,     1);
    STEP(k + 1, 0);
  }
  asm volatile("s_waitcnt vmcnt(0)" ::: "memory");   // drain dead tail issues

#undef STEP
#undef MFMA16
#undef CONVA
#undef CVT1
#undef ISSUEB
#undef ISSUEA

  // epilogue: bf16 h1 write + fused transposed column stats (per block,wm partials)
  #pragma unroll
  for (int fn = 0; fn < 4; fn++){
    int c = wn * 64 + fn * 16 + cl;
    float sb = fsign(b1[c]);
    float s = 0.f, q = 0.f;
    #pragma unroll
    for (int fm = 0; fm < 2; fm++){
      int rbase = row0 + wm * 32 + fm * 16 + g * 4;
      #pragma unroll
      for (int i = 0; i < 4; i++){
        float v = acc[fm][fn][i] + sb;
        h1[(size_t)(rbase + i) * 256 + c] = (unsigned short)f2bf(v);
        s += v; q += v * v;
      }
    }
    s += __shfl_xor(s, 16, 64); s += __shfl_xor(s, 32, 64);
    q += __shfl_xor(q, 16, 64); q += __shfl_xor(q, 32, 64);
    if (g == 0){
      part1s[(size_t)c * 512 + blockIdx.x * 2 + wm] = s;
      part1q[(size_t)c * 512 + blockIdx.x * 2 + wm] = q;
    }
  }
}

// ---------------- BN params from transposed partials ------------------------------------------
template<int COLS, int NBLK>
__global__ __launch_bounds__(64) void params_k(
    const float* __restrict__ ps, const float* __restrict__ pq,
    const float* __restrict__ g, const float* __restrict__ be,
    float* __restrict__ ab){
  int j = blockIdx.x * 64 + threadIdx.x;
  const f4* vs = (const f4*)(ps + (size_t)j * NBLK);
  const f4* vq = (const f4*)(pq + (size_t)j * NBLK);
  f4 s4 = {0,0,0,0}, q4 = {0,0,0,0};
  #pragma unroll 8
  for (int b = 0; b < NBLK/4; b++){ s4 += vs[b]; q4 += vq[b]; }
  float s = s4[0]+s4[1]+s4[2]+s4[3];
  float q = q4[0]+q4[1]+q4[2]+q4[3];
  float mu  = s * (1.f/16384.f);
  float var = q * (1.f/16384.f) - mu*mu;
  float a   = g[j] * rsqrtf(var + 1e-5f);
  ab[j] = a;
  ab[COLS + j] = be[j] - mu*a;
}

// ---------------- GEMM2: h2(bf16) = clip(BN1(h1)) @ signW2^T + sign(b2), fused stats -----------
__global__ __launch_bounds__(512) void gemm2_k(
    const unsigned short* __restrict__ h1, const unsigned short* __restrict__ w2s,
    const float* __restrict__ b2, const float* __restrict__ ab1,
    unsigned short* __restrict__ h2, float* __restrict__ part2s, float* __restrict__ part2q)
{
  __shared__ __align__(16) char lds[32768];
  __shared__ __align__(16) float a1l[256];
  __shared__ __align__(16) float c1l[256];
  const int tid  = threadIdx.x;
  const int lane = tid & 63;
  const int wid  = tid >> 6;          // 0..7 -> cols wid*16..+15
  const int cl   = lane & 15;
  const int g    = lane >> 4;
  const int klo  = g * 8;
  const int row0 = blockIdx.x * 64;

  if (tid < 256) a1l[tid] = ab1[tid];
  else           c1l[tid - 256] = ab1[tid];

  const int am  = tid >> 3;
  const int ak0 = (tid & 7) * 8;
  const unsigned short* hA = h1 + (size_t)(row0 + am) * 256 + ak0;
  const int aw = ((am * 128) + (ak0 * 2)) ^ ((am & 7) << 4);
  const unsigned short* wbase = w2s + (size_t)(wid * 16 + cl) * 256 + klo;

  u4 q0 = *(const u4*)(hA);
  u4 q1 = *(const u4*)(hA + 64);
  u4 q2 = *(const u4*)(hA + 128);
  u4 q3 = *(const u4*)(hA + 192);
  short8 Bq0, Bq1, Br0, Br1;
  Bq0 = *(const short8*)(wbase);
  Bq1 = *(const short8*)(wbase + 32);

  BARRIER();                 // a1l/c1l visible

#define TRW(KB, RAW) do { \
    f4 _a0 = *(const f4*)(&a1l[(KB)*64 + ak0]); \
    f4 _a1 = *(const f4*)(&a1l[(KB)*64 + ak0 + 4]); \
    f4 _c0 = *(const f4*)(&c1l[(KB)*64 + ak0]); \
    f4 _c1 = *(const f4*)(&c1l[(KB)*64 + ak0 + 4]); \
    float _t0 = hclip(_a0[0]*bflo(RAW.x) + _c0[0]); \
    float _t1 = hclip(_a0[1]*bfhi(RAW.x) + _c0[1]); \
    float _t2 = hclip(_a0[2]*bflo(RAW.y) + _c0[2]); \
    float _t3 = hclip(_a0[3]*bfhi(RAW.y) + _c0[3]); \
    float _t4 = hclip(_a1[0]*bflo(RAW.z) + _c1[0]); \
    float _t5 = hclip(_a1[1]*bfhi(RAW.z) + _c1[1]); \
    float _t6 = hclip(_a1[2]*bflo(RAW.w) + _c1[2]); \
    float _t7 = hclip(_a1[3]*bfhi(RAW.w) + _c1[3]); \
    u4 _v; \
    _v.x = f2bf(_t0) | (f2bf(_t1) << 16); \
    _v.y = f2bf(_t2) | (f2bf(_t3) << 16); \
    _v.z = f2bf(_t4) | (f2bf(_t5) << 16); \
    _v.w = f2bf(_t6) | (f2bf(_t7) << 16); \
    *(u4*)(lds + (KB)*8192 + aw) = _v; \
  } while(0)

  TRW(0, q0); TRW(1, q1); TRW(2, q2); TRW(3, q3);
#undef TRW
  BARRIER();

  f4 acc[4];
  const f4 z = {0.f, 0.f, 0.f, 0.f};
  #pragma unroll
  for (int i = 0; i < 4; i++) acc[i] = z;

#define LOADB2(P, KB) do { \
    B##P##0 = *(const short8*)(wbase + (KB)*64); \
    B##P##1 = *(const short8*)(wbase + (KB)*64 + 32); \
  } while(0)

#define COMP2(BASE, P) do { \
    const char* _ab = (const char*)(BASE); \
    short8 _af[4][2]; \
    _Pragma("unroll") \
    for (int fm = 0; fm < 4; fm++){ \
      int _m = fm*16 + cl; \
      _af[fm][0] = *(const short8*)(_ab + ((_m*128 + klo*2) ^ ((_m & 7) << 4))); \
      _af[fm][1] = *(const short8*)(_ab + ((_m*128 + (32 + klo)*2) ^ ((_m & 7) << 4))); \
    } \
    _Pragma("unroll") \
    for (int fm = 0; fm < 4; fm++){ \
      acc[fm] = __builtin_amdgcn_mfma_f32_16x16x32_bf16(_af[fm][0], B##P##0, acc[fm], 0, 0, 0); \
      acc[fm] = __builtin_amdgcn_mfma_f32_16x16x32_bf16(_af[fm][1], B##P##1, acc[fm], 0, 0, 0); \
    } \
  } while(0)

  LOADB2(r, 1);
  COMP2(lds,         q);
  LOADB2(q, 2);
  COMP2(lds +  8192, r);
  LOADB2(r, 3);
  COMP2(lds + 16384, q);
  COMP2(lds + 24576, r);
#undef COMP2
#undef LOADB2

  {
    int c = wid*16 + cl;
    float sb = fsign(b2[c]);
    float s = 0.f, q = 0.f;
    #pragma unroll
    for (int fm = 0; fm < 4; fm++){
      int rbase = row0 + fm*16 + g*4;
      #pragma unroll
      for (int i = 0; i < 4; i++){
        float v = acc[fm][i] + sb;
        h2[(size_t)(rbase + i)*128 + c] = (unsigned short)f2bf(v);
        s += v; q += v*v;
      }
    }
    s += __shfl_xor(s, 16, 64); s += __shfl_xor(s, 32, 64);
    q += __shfl_xor(q, 16, 64); q += __shfl_xor(q, 32, 64);
    if (g == 0){
      part2s[c*256 + blockIdx.x] = s;
      part2q[c*256 + blockIdx.x] = q;
    }
  }
}

// ---------------- final: out = clip(BN2(h2)) @ W4^T + b4, BN2 params fused ---------------------
__global__ __launch_bounds__(128) void final_k(
    const unsigned short* __restrict__ h2,
    const float* __restrict__ part2s, const float* __restrict__ part2q,
    const float* __restrict__ g2, const float* __restrict__ be2,
    const float* __restrict__ W4, const float* __restrict__ b4,
    float* __restrict__ out)
{
  __shared__ __align__(16) float W4l[12*128];
  __shared__ __align__(16) float a2l[128];
  __shared__ __align__(16) float c2l[128];
  const int t = threadIdx.x;
  #pragma unroll
  for (int i = 0; i < 3; i++)
    *(f4*)&W4l[(i*128 + t)*4] = *(const f4*)(W4 + (i*128 + t)*4);
  {
    const f4* vs = (const f4*)(part2s + t*256);
    const f4* vq = (const f4*)(part2q + t*256);
    f4 s4 = {0,0,0,0}, q4 = {0,0,0,0};
    #pragma unroll 8
    for (int b = 0; b < 64; b++){ s4 += vs[b]; q4 += vq[b]; }
    float s = s4[0]+s4[1]+s4[2]+s4[3];
    float q = q4[0]+q4[1]+q4[2]+q4[3];
    float mu  = s * (1.f/16384.f);
    float var = q * (1.f/16384.f) - mu*mu;
    float a   = g2[t] * rsqrtf(var + 1e-5f);
    a2l[t] = a;
    c2l[t] = be2[t] - mu*a;
  }
  __syncthreads();

  const int r = blockIdx.x * 128 + t;
  const u4* hp = (const u4*)(h2 + (size_t)r * 128);
  u4 hv0 = hp[0], hv1 = hp[1], hv2 = hp[2],  hv3 = hp[3];
  u4 hv4 = hp[4], hv5 = hp[5], hv6 = hp[6],  hv7 = hp[7];
  u4 hv8 = hp[8], hv9 = hp[9], hv10 = hp[10], hv11 = hp[11];
  u4 hv12 = hp[12], hv13 = hp[13], hv14 = hp[14], hv15 = hp[15];

  float acc[12];
  #pragma unroll
  for (int o = 0; o < 12; o++) acc[o] = b4[o];

#define FPROC(HV, J) do { \
    f4 a0 = *(const f4*)&a2l[(J)*8];     f4 a1 = *(const f4*)&a2l[(J)*8 + 4]; \
    f4 c0 = *(const f4*)&c2l[(J)*8];     f4 c1 = *(const f4*)&c2l[(J)*8 + 4]; \
    float tt0 = hclip(a0[0]*bflo(HV.x) + c0[0]); \
    float tt1 = hclip(a0[1]*bfhi(HV.x) + c0[1]); \
    float tt2 = hclip(a0[2]*bflo(HV.y) + c0[2]); \
    float tt3 = hclip(a0[3]*bfhi(HV.y) + c0[3]); \
    float tt4 = hclip(a1[0]*bflo(HV.z) + c1[0]); \
    float tt5 = hclip(a1[1]*bfhi(HV.z) + c1[1]); \
    float tt6 = hclip(a1[2]*bflo(HV.w) + c1[2]); \
    float tt7 = hclip(a1[3]*bfhi(HV.w) + c1[3]); \
    _Pragma("unroll") \
    for (int o = 0; o < 12; o++){ \
      f4 w0 = *(const f4*)&W4l[o*128 + (J)*8]; \
      f4 w1 = *(const f4*)&W4l[o*128 + (J)*8 + 4]; \
      acc[o] += tt0*w0[0] + tt1*w0[1] + tt2*w0[2] + tt3*w0[3] \
              + tt4*w1[0] + tt5*w1[1] + tt6*w1[2] + tt7*w1[3]; \
    } \
  } while(0)

  FPROC(hv0, 0);  FPROC(hv1, 1);  FPROC(hv2, 2);   FPROC(hv3, 3);
  FPROC(hv4, 4);  FPROC(hv5, 5);  FPROC(hv6, 6);   FPROC(hv7, 7);
  FPROC(hv8, 8);  FPROC(hv9, 9);  FPROC(hv10, 10); FPROC(hv11, 11);
  FPROC(hv12, 12); FPROC(hv13, 13); FPROC(hv14, 14); FPROC(hv15, 15);
#undef FPROC

  #pragma unroll
  for (int o = 0; o < 12; o++) out[(size_t)r*12 + o] = acc[o];
}

// ---------------- launch ----------------
extern "C" void kernel_launch(void* const* d_in, const int* in_sizes, int n_in,
                              void* d_out, int out_size, void* d_ws, size_t ws_size,
                              hipStream_t stream)
{
  const float* x   = (const float*)d_in[0];
  const float* W1  = (const float*)d_in[1];
  const float* b1  = (const float*)d_in[2];
  const float* g1  = (const float*)d_in[3];
  const float* be1 = (const float*)d_in[4];
  const float* W2  = (const float*)d_in[5];
  const float* b2  = (const float*)d_in[6];
  const float* g2  = (const float*)d_in[7];
  const float* be2 = (const float*)d_in[8];
  const float* W4  = (const float*)d_in[9];
  const float* b4  = (const float*)d_in[10];
  float* out = (float*)d_out;

  char* ws = (char*)d_ws;
  unsigned short* h1     = (unsigned short*)(ws);              //  8 MB  [16384,256] bf16
  unsigned short* h2     = (unsigned short*)(ws + 8388608);    //  4 MB  [16384,128] bf16
  unsigned short* w1f    = (unsigned short*)(ws + 12582912);   //  2 MB  frag-major
  unsigned short* w2s    = (unsigned short*)(ws + 14680064);   // 64 KB  [128,256] bf16
  float*          part1s = (float*)(ws + 14745600);            // 512 KB [256][512]
  float*          part1q = (float*)(ws + 15269888);            // 512 KB
  float*          part2s = (float*)(ws + 15794176);            // 128 KB [128][256]
  float*          part2q = (float*)(ws + 15925248);            // 128 KB
  float*          ab1    = (float*)(ws + 16056320);            // a1[256], c1[256]

  prep_sign_k<<<528, 256, 0, stream>>>(W1, w1f, W2, w2s);
  gemm1_k<<<256, 512, 0, stream>>>(x, w1f, b1, h1, part1s, part1q);
  params_k<256, 512><<<4, 64, 0, stream>>>(part1s, part1q, g1, be1, ab1);
  gemm2_k<<<256, 512, 0, stream>>>(h1, w2s, b2, ab1, h2, part2s, part2q);
  final_k<<<128, 128, 0, stream>>>(h2, part2s, part2q, g2, be2, W4, b4, out);
}

// Round 18
// 135.898 us; speedup vs baseline: 1.7077x; 1.7077x over previous
//
#include <hip/hip_runtime.h>
#include <cstddef>

typedef __attribute__((ext_vector_type(8))) short short8;
typedef __attribute__((ext_vector_type(4))) float f4;
typedef __attribute__((ext_vector_type(4))) unsigned int u4;
typedef __attribute__((ext_vector_type(2))) unsigned int u2;

__device__ __forceinline__ unsigned int f2bf(float f){
  unsigned int u = __float_as_uint(f);
  u += 0x7fffu + ((u >> 16) & 1u);   // RNE to bf16
  return u >> 16;
}
__device__ __forceinline__ float bflo(unsigned int w){ return __uint_as_float((w & 0xFFFFu) << 16); }
__device__ __forceinline__ float bfhi(unsigned int w){ return __uint_as_float(w & 0xFFFF0000u); }
__device__ __forceinline__ float fsign(float x){ return (x > 0.f) ? 1.f : ((x < 0.f) ? -1.f : 0.f); }
__device__ __forceinline__ float hclip(float x){ return fminf(1.f, fmaxf(-1.f, x)); }

#define SB0 __builtin_amdgcn_sched_barrier(0)

#define BARRIER() do { \
    SB0; \
    asm volatile("s_waitcnt lgkmcnt(0)" ::: "memory"); \
    __builtin_amdgcn_s_barrier(); \
    asm volatile("" ::: "memory"); \
    SB0; \
  } while(0)

#define VBAR(N) do { \
    SB0; \
    asm volatile("s_waitcnt vmcnt(" #N ") lgkmcnt(0)" ::: "memory"); \
    __builtin_amdgcn_s_barrier(); \
    asm volatile("" ::: "memory"); \
    SB0; \
  } while(0)

#define GL16(gp, lp) __builtin_amdgcn_global_load_lds( \
    (const __attribute__((address_space(1))) void*)(gp), \
    (__attribute__((address_space(3))) void*)(lp), 16, 0, 0)

// ---------------- prep: sign weights -> bf16 {+1,-1,0} ----------------------------------------
// W1 -> fragment layout W'[k>>5][g=(k>>3)&3][n][k&7]; W2 -> row-major.
__global__ void prep_sign_k(const float* __restrict__ W1, unsigned short* __restrict__ w1s,
                            const float* __restrict__ W2, unsigned short* __restrict__ w2s){
  int i = (blockIdx.x * blockDim.x + threadIdx.x) * 8;
  if (i < 1048576){
    int n = i >> 12, k = i & 4095;
    f4 a = *(const f4*)(W1 + i);
    f4 b = *(const f4*)(W1 + i + 4);
    u4 v;
    v.x = (unsigned)((a[0] > 0.f) ? 0x3F80u : (a[0] < 0.f ? 0xBF80u : 0u))
        | ((unsigned)((a[1] > 0.f) ? 0x3F80u : (a[1] < 0.f ? 0xBF80u : 0u)) << 16);
    v.y = (unsigned)((a[2] > 0.f) ? 0x3F80u : (a[2] < 0.f ? 0xBF80u : 0u))
        | ((unsigned)((a[3] > 0.f) ? 0x3F80u : (a[3] < 0.f ? 0xBF80u : 0u)) << 16);
    v.z = (unsigned)((b[0] > 0.f) ? 0x3F80u : (b[0] < 0.f ? 0xBF80u : 0u))
        | ((unsigned)((b[1] > 0.f) ? 0x3F80u : (b[1] < 0.f ? 0xBF80u : 0u)) << 16);
    v.w = (unsigned)((b[2] > 0.f) ? 0x3F80u : (b[2] < 0.f ? 0xBF80u : 0u))
        | ((unsigned)((b[3] > 0.f) ? 0x3F80u : (b[3] < 0.f ? 0xBF80u : 0u)) << 16);
    size_t ob = ((size_t)((k >> 5) * 4 + ((k >> 3) & 3)) * 256 + (size_t)n) * 16;
    *(u4*)((char*)w1s + ob) = v;
  } else {
    int off = i - 1048576;
    if (off >= 32768) return;
    f4 a = *(const f4*)(W2 + off);
    f4 b = *(const f4*)(W2 + off + 4);
    u4 v;
    v.x = (unsigned)((a[0] > 0.f) ? 0x3F80u : (a[0] < 0.f ? 0xBF80u : 0u))
        | ((unsigned)((a[1] > 0.f) ? 0x3F80u : (a[1] < 0.f ? 0xBF80u : 0u)) << 16);
    v.y = (unsigned)((a[2] > 0.f) ? 0x3F80u : (a[2] < 0.f ? 0xBF80u : 0u))
        | ((unsigned)((a[3] > 0.f) ? 0x3F80u : (a[3] < 0.f ? 0xBF80u : 0u)) << 16);
    v.z = (unsigned)((b[0] > 0.f) ? 0x3F80u : (b[0] < 0.f ? 0xBF80u : 0u))
        | ((unsigned)((b[1] > 0.f) ? 0x3F80u : (b[1] < 0.f ? 0xBF80u : 0u)) << 16);
    v.w = (unsigned)((b[2] > 0.f) ? 0x3F80u : (b[2] < 0.f ? 0xBF80u : 0u))
        | ((unsigned)((b[3] > 0.f) ? 0x3F80u : (b[3] < 0.f ? 0xBF80u : 0u)) << 16);
    *(u4*)(w2s + off) = v;
  }
}

// ---------------- GEMM1 (split-K=2): p[kh] = x[:,half] @ signW1[:,half]^T ----------------------
__global__ __launch_bounds__(512, 4) void gemm1_k(
    const float* __restrict__ x, const unsigned short* __restrict__ w1s,
    float* __restrict__ pout)
{
  __shared__ __align__(16) char lds[75776];   // A: 2x5120 @0 ; B: 4x16384 @10240
  const int tid  = threadIdx.x;
  const int lane = tid & 63;
  const int wid  = tid >> 6;
  const int wm   = wid >> 2;
  const int wn   = wid & 3;
  const int cl   = lane & 15;
  const int g    = lane >> 4;
  const int gm   = blockIdx.x >> 1;
  const int kh   = blockIdx.x & 1;
  const int row0 = gm * 64;
  float* pk = pout + (size_t)kh * 4194304;

  const int am = tid >> 3, s = tid & 7;
  const float* xA = x + (size_t)(row0 + am) * 4096 + kh * 2048 + s * 4;
  const int aw = am * 80 + (s >> 1) * 16 + (s & 1) * 8;

  const int o0 = tid * 16;
  const int o1 = 8192 + tid * 16;
  const size_t sB0 = ((size_t)(o0 >> 12) * 256 + (size_t)((o0 >> 4) & 255)) * 16;
  const size_t sB1 = ((size_t)(o1 >> 12) * 256 + (size_t)((o1 >> 4) & 255)) * 16;
  const char* w1p = (const char*)w1s + (size_t)kh * 1048576;

  int afo[2], bfo[4];
  #pragma unroll
  for (int fm = 0; fm < 2; fm++)
    afo[fm] = (wm * 32 + fm * 16 + cl) * 80 + g * 16;
  #pragma unroll
  for (int fn = 0; fn < 4; fn++)
    bfo[fn] = g * 4096 + (wn * 64 + fn * 16 + cl) * 16;

  f4 acc[2][4];
  const f4 z = {0.f, 0.f, 0.f, 0.f};
  #pragma unroll
  for (int i = 0; i < 2; i++)
    #pragma unroll
    for (int j = 0; j < 4; j++) acc[i][j] = z;

  f4 rA0, rA1, rA2, rA3;

#define ISSUEA(S, K) do { rA##S = *(const f4*)(xA + (size_t)(K) * 32); } while(0)

#define ISSUEB(BI, K) do { \
    const char* _src = w1p + (size_t)(K) * 16384; \
    char* _dst = lds + 10240 + (BI) * 16384; \
    GL16(_src + sB0, _dst + o0); \
    GL16(_src + sB1, _dst + o1); \
  } while(0)

#define PACKA(S, AB) do { \
    u2 _v; \
    _v.x = f2bf(rA##S[0]) | (f2bf(rA##S[1]) << 16); \
    _v.y = f2bf(rA##S[2]) | (f2bf(rA##S[3]) << 16); \
    *(u2*)(lds + (AB) * 5120 + aw) = _v; \
  } while(0)

#define COMPUTE(AB, BB) do { \
    const char* _ab = lds + (AB) * 5120; \
    const char* _bb = lds + 10240 + (BB) * 16384; \
    short8 _af0 = *(const short8*)(_ab + afo[0]); \
    short8 _af1 = *(const short8*)(_ab + afo[1]); \
    short8 _bf0 = *(const short8*)(_bb + bfo[0]); \
    short8 _bf1 = *(const short8*)(_bb + bfo[1]); \
    short8 _bf2 = *(const short8*)(_bb + bfo[2]); \
    short8 _bf3 = *(const short8*)(_bb + bfo[3]); \
    __builtin_amdgcn_s_setprio(1); \
    acc[0][0] = __builtin_amdgcn_mfma_f32_16x16x32_bf16(_af0, _bf0, acc[0][0], 0, 0, 0); \
    acc[0][1] = __builtin_amdgcn_mfma_f32_16x16x32_bf16(_af0, _bf1, acc[0][1], 0, 0, 0); \
    acc[0][2] = __builtin_amdgcn_mfma_f32_16x16x32_bf16(_af0, _bf2, acc[0][2], 0, 0, 0); \
    acc[0][3] = __builtin_amdgcn_mfma_f32_16x16x32_bf16(_af0, _bf3, acc[0][3], 0, 0, 0); \
    acc[1][0] = __builtin_amdgcn_mfma_f32_16x16x32_bf16(_af1, _bf0, acc[1][0], 0, 0, 0); \
    acc[1][1] = __builtin_amdgcn_mfma_f32_16x16x32_bf16(_af1, _bf1, acc[1][1], 0, 0, 0); \
    acc[1][2] = __builtin_amdgcn_mfma_f32_16x16x32_bf16(_af1, _bf2, acc[1][2], 0, 0, 0); \
    acc[1][3] = __builtin_amdgcn_mfma_f32_16x16x32_bf16(_af1, _bf3, acc[1][3], 0, 0, 0); \
    __builtin_amdgcn_s_setprio(0); \
  } while(0)

#define STEP(K, SI, SP, ABR, ABW, BBR, BBW) do { \
    ISSUEB(BBW, ((K) + 2 < 64) ? (K) + 2 : 63); \
    ISSUEA(SI, ((K) + 4 < 64) ? (K) + 4 : 63); \
    SB0; \
    COMPUTE(ABR, BBR); \
    SB0; \
    if ((K) < 63) PACKA(SP, ABW); \
    VBAR(4); \
  } while(0)

  ISSUEA(0, 0);
  ISSUEB(0, 0); ISSUEB(1, 1);
  ISSUEA(1, 1); ISSUEA(2, 2); ISSUEA(3, 3);
  SB0;
  PACKA(0, 0);
  VBAR(3);

  #pragma unroll 1
  for (int kk = 0; kk < 64; kk += 4){
    STEP(kk + 0, 0, 1, 0, 1, 0, 2);
    STEP(kk + 1, 1, 2, 1, 0, 1, 3);
    STEP(kk + 2, 2, 3, 0, 1, 2, 0);
    STEP(kk + 3, 3, 0, 1, 0, 3, 1);
  }
  asm volatile("s_waitcnt vmcnt(0)" ::: "memory");

#undef STEP
#undef COMPUTE
#undef PACKA
#undef ISSUEB
#undef ISSUEA

  #pragma unroll
  for (int fn = 0; fn < 4; fn++){
    int c = wn * 64 + fn * 16 + cl;
    #pragma unroll
    for (int fm = 0; fm < 2; fm++){
      int rbase = row0 + wm * 32 + fm * 16 + g * 4;
      #pragma unroll
      for (int i = 0; i < 4; i++)
        pk[(size_t)(rbase + i) * 256 + c] = acc[fm][fn][i];
    }
  }
}

// ---------------- merge: h1 = bf16(p0+p1+sign(b1)); fused transposed col-stats -----------------
__global__ __launch_bounds__(256) void merge_k(
    const float* __restrict__ p0, const float* __restrict__ p1,
    const float* __restrict__ b1, unsigned short* __restrict__ h1,
    float* __restrict__ part1s, float* __restrict__ part1q)
{
  __shared__ __align__(16) f4 sred[256];
  __shared__ __align__(16) f4 qred[256];
  const int t  = threadIdx.x;
  const int b  = blockIdx.x;
  const int c0 = (t & 63) * 4;
  const int rg = t >> 6;
  const int r0 = b * 64 + rg * 16;

  f4 bv = *(const f4*)(b1 + c0);
  f4 sb = { fsign(bv[0]), fsign(bv[1]), fsign(bv[2]), fsign(bv[3]) };

  f4 s4 = {0,0,0,0}, q4 = {0,0,0,0};
  #pragma unroll 4
  for (int i = 0; i < 16; i++){
    size_t off = (size_t)(r0 + i) * 256 + c0;
    f4 v0 = *(const f4*)(p0 + off);
    f4 v1 = *(const f4*)(p1 + off);
    f4 v = v0 + v1 + sb;
    u2 pkk;
    pkk.x = f2bf(v[0]) | (f2bf(v[1]) << 16);
    pkk.y = f2bf(v[2]) | (f2bf(v[3]) << 16);
    *(u2*)(h1 + off) = pkk;
    s4 += v;
    q4 += v * v;
  }
  sred[t] = s4; qred[t] = q4;
  __syncthreads();
  if (t < 64){
    f4 st = sred[t] + sred[t + 64] + sred[t + 128] + sred[t + 192];
    f4 qt = qred[t] + qred[t + 64] + qred[t + 128] + qred[t + 192];
    #pragma unroll
    for (int i = 0; i < 4; i++){
      part1s[(size_t)(t * 4 + i) * 256 + b] = st[i];
      part1q[(size_t)(t * 4 + i) * 256 + b] = qt[i];
    }
  }
}

// ---------------- BN params from transposed partials ------------------------------------------
template<int COLS, int NBLK>
__global__ __launch_bounds__(64) void params_k(
    const float* __restrict__ ps, const float* __restrict__ pq,
    const float* __restrict__ g, const float* __restrict__ be,
    float* __restrict__ ab){
  int j = blockIdx.x * 64 + threadIdx.x;
  const f4* vs = (const f4*)(ps + (size_t)j * NBLK);
  const f4* vq = (const f4*)(pq + (size_t)j * NBLK);
  f4 s4 = {0,0,0,0}, q4 = {0,0,0,0};
  #pragma unroll 8
  for (int b = 0; b < NBLK/4; b++){ s4 += vs[b]; q4 += vq[b]; }
  float s = s4[0]+s4[1]+s4[2]+s4[3];
  float q = q4[0]+q4[1]+q4[2]+q4[3];
  float mu  = s * (1.f/16384.f);
  float var = q * (1.f/16384.f) - mu*mu;
  float a   = g[j] * rsqrtf(var + 1e-5f);
  ab[j] = a;
  ab[COLS + j] = be[j] - mu*a;
}

// ---------------- GEMM2: h2(bf16) = clip(BN1(h1)) @ signW2^T + sign(b2), fused stats -----------
__global__ __launch_bounds__(512) void gemm2_k(
    const unsigned short* __restrict__ h1, const unsigned short* __restrict__ w2s,
    const float* __restrict__ b2, const float* __restrict__ ab1,
    unsigned short* __restrict__ h2, float* __restrict__ part2s, float* __restrict__ part2q)
{
  __shared__ __align__(16) char lds[32768];
  __shared__ __align__(16) float a1l[256];
  __shared__ __align__(16) float c1l[256];
  const int tid  = threadIdx.x;
  const int lane = tid & 63;
  const int wid  = tid >> 6;
  const int cl   = lane & 15;
  const int g    = lane >> 4;
  const int klo  = g * 8;
  const int row0 = blockIdx.x * 64;

  if (tid < 256) a1l[tid] = ab1[tid];
  else           c1l[tid - 256] = ab1[tid];

  const int am  = tid >> 3;
  const int ak0 = (tid & 7) * 8;
  const unsigned short* hA = h1 + (size_t)(row0 + am) * 256 + ak0;
  const int aw = ((am * 128) + (ak0 * 2)) ^ ((am & 7) << 4);
  const unsigned short* wbase = w2s + (size_t)(wid * 16 + cl) * 256 + klo;

  u4 q0 = *(const u4*)(hA);
  u4 q1 = *(const u4*)(hA + 64);
  u4 q2 = *(const u4*)(hA + 128);
  u4 q3 = *(const u4*)(hA + 192);
  short8 Bq0, Bq1, Br0, Br1;
  Bq0 = *(const short8*)(wbase);
  Bq1 = *(const short8*)(wbase + 32);

  BARRIER();

#define TRW(KB, RAW) do { \
    f4 _a0 = *(const f4*)(&a1l[(KB)*64 + ak0]); \
    f4 _a1 = *(const f4*)(&a1l[(KB)*64 + ak0 + 4]); \
    f4 _c0 = *(const f4*)(&c1l[(KB)*64 + ak0]); \
    f4 _c1 = *(const f4*)(&c1l[(KB)*64 + ak0 + 4]); \
    float _t0 = hclip(_a0[0]*bflo(RAW.x) + _c0[0]); \
    float _t1 = hclip(_a0[1]*bfhi(RAW.x) + _c0[1]); \
    float _t2 = hclip(_a0[2]*bflo(RAW.y) + _c0[2]); \
    float _t3 = hclip(_a0[3]*bfhi(RAW.y) + _c0[3]); \
    float _t4 = hclip(_a1[0]*bflo(RAW.z) + _c1[0]); \
    float _t5 = hclip(_a1[1]*bfhi(RAW.z) + _c1[1]); \
    float _t6 = hclip(_a1[2]*bflo(RAW.w) + _c1[2]); \
    float _t7 = hclip(_a1[3]*bfhi(RAW.w) + _c1[3]); \
    u4 _v; \
    _v.x = f2bf(_t0) | (f2bf(_t1) << 16); \
    _v.y = f2bf(_t2) | (f2bf(_t3) << 16); \
    _v.z = f2bf(_t4) | (f2bf(_t5) << 16); \
    _v.w = f2bf(_t6) | (f2bf(_t7) << 16); \
    *(u4*)(lds + (KB)*8192 + aw) = _v; \
  } while(0)

  TRW(0, q0); TRW(1, q1); TRW(2, q2); TRW(3, q3);
#undef TRW
  BARRIER();

  f4 acc[4];
  const f4 z = {0.f, 0.f, 0.f, 0.f};
  #pragma unroll
  for (int i = 0; i < 4; i++) acc[i] = z;

#define LOADB2(P, KB) do { \
    B##P##0 = *(const short8*)(wbase + (KB)*64); \
    B##P##1 = *(const short8*)(wbase + (KB)*64 + 32); \
  } while(0)

#define COMP2(BASE, P) do { \
    const char* _ab = (const char*)(BASE); \
    short8 _af[4][2]; \
    _Pragma("unroll") \
    for (int fm = 0; fm < 4; fm++){ \
      int _m = fm*16 + cl; \
      _af[fm][0] = *(const short8*)(_ab + ((_m*128 + klo*2) ^ ((_m & 7) << 4))); \
      _af[fm][1] = *(const short8*)(_ab + ((_m*128 + (32 + klo)*2) ^ ((_m & 7) << 4))); \
    } \
    _Pragma("unroll") \
    for (int fm = 0; fm < 4; fm++){ \
      acc[fm] = __builtin_amdgcn_mfma_f32_16x16x32_bf16(_af[fm][0], B##P##0, acc[fm], 0, 0, 0); \
      acc[fm] = __builtin_amdgcn_mfma_f32_16x16x32_bf16(_af[fm][1], B##P##1, acc[fm], 0, 0, 0); \
    } \
  } while(0)

  LOADB2(r, 1);
  COMP2(lds,         q);
  LOADB2(q, 2);
  COMP2(lds +  8192, r);
  LOADB2(r, 3);
  COMP2(lds + 16384, q);
  COMP2(lds + 24576, r);
#undef COMP2
#undef LOADB2

  {
    int c = wid*16 + cl;
    float sb = fsign(b2[c]);
    float s = 0.f, q = 0.f;
    #pragma unroll
    for (int fm = 0; fm < 4; fm++){
      int rbase = row0 + fm*16 + g*4;
      #pragma unroll
      for (int i = 0; i < 4; i++){
        float v = acc[fm][i] + sb;
        h2[(size_t)(rbase + i)*128 + c] = (unsigned short)f2bf(v);
        s += v; q += v*v;
      }
    }
    s += __shfl_xor(s, 16, 64); s += __shfl_xor(s, 32, 64);
    q += __shfl_xor(q, 16, 64); q += __shfl_xor(q, 32, 64);
    if (g == 0){
      part2s[c*256 + blockIdx.x] = s;
      part2q[c*256 + blockIdx.x] = q;
    }
  }
}

// ---------------- final: out = clip(BN2(h2)) @ W4^T + b4, BN2 params fused ---------------------
__global__ __launch_bounds__(128) void final_k(
    const unsigned short* __restrict__ h2,
    const float* __restrict__ part2s, const float* __restrict__ part2q,
    const float* __restrict__ g2, const float* __restrict__ be2,
    const float* __restrict__ W4, const float* __restrict__ b4,
    float* __restrict__ out)
{
  __shared__ __align__(16) float W4l[12*128];
  __shared__ __align__(16) float a2l[128];
  __shared__ __align__(16) float c2l[128];
  const int t = threadIdx.x;
  #pragma unroll
  for (int i = 0; i < 3; i++)
    *(f4*)&W4l[(i*128 + t)*4] = *(const f4*)(W4 + (i*128 + t)*4);
  {
    const f4* vs = (const f4*)(part2s + t*256);
    const f4* vq = (const f4*)(part2q + t*256);
    f4 s4 = {0,0,0,0}, q4 = {0,0,0,0};
    #pragma unroll 8
    for (int b = 0; b < 64; b++){ s4 += vs[b]; q4 += vq[b]; }
    float s = s4[0]+s4[1]+s4[2]+s4[3];
    float q = q4[0]+q4[1]+q4[2]+q4[3];
    float mu  = s * (1.f/16384.f);
    float var = q * (1.f/16384.f) - mu*mu;
    float a   = g2[t] * rsqrtf(var + 1e-5f);
    a2l[t] = a;
    c2l[t] = be2[t] - mu*a;
  }
  __syncthreads();

  const int r = blockIdx.x * 128 + t;
  const u4* hp = (const u4*)(h2 + (size_t)r * 128);
  u4 hv0 = hp[0], hv1 = hp[1], hv2 = hp[2],  hv3 = hp[3];
  u4 hv4 = hp[4], hv5 = hp[5], hv6 = hp[6],  hv7 = hp[7];
  u4 hv8 = hp[8], hv9 = hp[9], hv10 = hp[10], hv11 = hp[11];
  u4 hv12 = hp[12], hv13 = hp[13], hv14 = hp[14], hv15 = hp[15];

  float acc[12];
  #pragma unroll
  for (int o = 0; o < 12; o++) acc[o] = b4[o];

#define FPROC(HV, J) do { \
    f4 a0 = *(const f4*)&a2l[(J)*8];     f4 a1 = *(const f4*)&a2l[(J)*8 + 4]; \
    f4 c0 = *(const f4*)&c2l[(J)*8];     f4 c1 = *(const f4*)&c2l[(J)*8 + 4]; \
    float tt0 = hclip(a0[0]*bflo(HV.x) + c0[0]); \
    float tt1 = hclip(a0[1]*bfhi(HV.x) + c0[1]); \
    float tt2 = hclip(a0[2]*bflo(HV.y) + c0[2]); \
    float tt3 = hclip(a0[3]*bfhi(HV.y) + c0[3]); \
    float tt4 = hclip(a1[0]*bflo(HV.z) + c1[0]); \
    float tt5 = hclip(a1[1]*bfhi(HV.z) + c1[1]); \
    float tt6 = hclip(a1[2]*bflo(HV.w) + c1[2]); \
    float tt7 = hclip(a1[3]*bfhi(HV.w) + c1[3]); \
    _Pragma("unroll") \
    for (int o = 0; o < 12; o++){ \
      f4 w0 = *(const f4*)&W4l[o*128 + (J)*8]; \
      f4 w1 = *(const f4*)&W4l[o*128 + (J)*8 + 4]; \
      acc[o] += tt0*w0[0] + tt1*w0[1] + tt2*w0[2] + tt3*w0[3] \
              + tt4*w1[0] + tt5*w1[1] + tt6*w1[2] + tt7*w1[3]; \
    } \
  } while(0)

  FPROC(hv0, 0);  FPROC(hv1, 1);  FPROC(hv2, 2);   FPROC(hv3, 3);
  FPROC(hv4, 4);  FPROC(hv5, 5);  FPROC(hv6, 6);   FPROC(hv7, 7);
  FPROC(hv8, 8);  FPROC(hv9, 9);  FPROC(hv10, 10); FPROC(hv11, 11);
  FPROC(hv12, 12); FPROC(hv13, 13); FPROC(hv14, 14); FPROC(hv15, 15);
#undef FPROC

  #pragma unroll
  for (int o = 0; o < 12; o++) out[(size_t)r*12 + o] = acc[o];
}

// ---------------- launch ----------------
extern "C" void kernel_launch(void* const* d_in, const int* in_sizes, int n_in,
                              void* d_out, int out_size, void* d_ws, size_t ws_size,
                              hipStream_t stream)
{
  const float* x   = (const float*)d_in[0];
  const float* W1  = (const float*)d_in[1];
  const float* b1  = (const float*)d_in[2];
  const float* g1  = (const float*)d_in[3];
  const float* be1 = (const float*)d_in[4];
  const float* W2  = (const float*)d_in[5];
  const float* b2  = (const float*)d_in[6];
  const float* g2  = (const float*)d_in[7];
  const float* be2 = (const float*)d_in[8];
  const float* W4  = (const float*)d_in[9];
  const float* b4  = (const float*)d_in[10];
  float* out = (float*)d_out;

  char* ws = (char*)d_ws;
  unsigned short* w1s    = (unsigned short*)(ws);              //  2 MB frag layout
  unsigned short* w2s    = (unsigned short*)(ws + 2097152);    // 64 KB
  unsigned short* h1     = (unsigned short*)(ws + 2162688);    //  8 MB
  float*          p0     = (float*)(ws + 10551296);            // 16 MB (p1 = p0 + 4M floats)
  float*          p1     = (float*)(ws + 27328512);            // 16 MB
  float*          part1s = (float*)(ws + 44105728);            // 256 KB
  float*          part1q = (float*)(ws + 44367872);            // 256 KB
  float*          ab1    = (float*)(ws + 44630016);            //   2 KB
  unsigned short* h2     = (unsigned short*)(ws + 44632064);   //   4 MB
  float*          part2s = (float*)(ws + 48826368);            // 128 KB
  float*          part2q = (float*)(ws + 48957440);            // 128 KB

  prep_sign_k<<<528, 256, 0, stream>>>(W1, w1s, W2, w2s);
  gemm1_k<<<512, 512, 0, stream>>>(x, w1s, p0);
  merge_k<<<256, 256, 0, stream>>>(p0, p1, b1, h1, part1s, part1q);
  params_k<256, 256><<<4, 64, 0, stream>>>(part1s, part1q, g1, be1, ab1);
  gemm2_k<<<256, 512, 0, stream>>>(h1, w2s, b2, ab1, h2, part2s, part2q);
  final_k<<<128, 128, 0, stream>>>(h2, part2s, part2q, g2, be2, W4, b4, out);
}

// Round 19
// 125.692 us; speedup vs baseline: 1.8464x; 1.0812x over previous
//
#include <hip/hip_runtime.h>
#include <cstddef>

typedef __attribute__((ext_vector_type(8))) short short8;
typedef __attribute__((ext_vector_type(4))) float f4;
typedef __attribute__((ext_vector_type(4))) unsigned int u4;

__device__ __forceinline__ unsigned int f2bf(float f){
  unsigned int u = __float_as_uint(f);
  u += 0x7fffu + ((u >> 16) & 1u);   // RNE to bf16
  return u >> 16;
}
__device__ __forceinline__ float bflo(unsigned int w){ return __uint_as_float((w & 0xFFFFu) << 16); }
__device__ __forceinline__ float bfhi(unsigned int w){ return __uint_as_float(w & 0xFFFF0000u); }
__device__ __forceinline__ float fsign(float x){ return (x > 0.f) ? 1.f : ((x < 0.f) ? -1.f : 0.f); }
__device__ __forceinline__ float hclip(float x){ return fminf(1.f, fmaxf(-1.f, x)); }

#define SB0 __builtin_amdgcn_sched_barrier(0)

// lgkm-only barrier (vmem loads stay in flight)
#define BARRIER() do { \
    SB0; \
    asm volatile("s_waitcnt lgkmcnt(0)" ::: "memory"); \
    __builtin_amdgcn_s_barrier(); \
    asm volatile("" ::: "memory"); \
    SB0; \
  } while(0)

// counted-vmcnt barrier
#define VBAR(N) do { \
    SB0; \
    asm volatile("s_waitcnt vmcnt(" #N ") lgkmcnt(0)" ::: "memory"); \
    __builtin_amdgcn_s_barrier(); \
    asm volatile("" ::: "memory"); \
    SB0; \
  } while(0)

// global -> LDS direct DMA, 16B per lane
#define GL16(gp, lp) __builtin_amdgcn_global_load_lds( \
    (const __attribute__((address_space(1))) void*)(gp), \
    (__attribute__((address_space(3))) void*)(lp), 16, 0, 0)

// ---------------- prep: sign(W1)+sign(W2) fp32 -> bf16 {+1,-1,0}, row-major -------------------
__global__ void prep_sign_k(const float* __restrict__ W1, unsigned short* __restrict__ w1s,
                            const float* __restrict__ W2, unsigned short* __restrict__ w2s){
  int i = (blockIdx.x * blockDim.x + threadIdx.x) * 8;
  const float* w; unsigned short* o; int off;
  if (i < 1048576){ w = W1; o = w1s; off = i; }
  else            { w = W2; o = w2s; off = i - 1048576; if (off >= 32768) return; }
  f4 a = *(const f4*)(w + off);
  f4 b = *(const f4*)(w + off + 4);
  unsigned short s[8];
  #pragma unroll
  for (int j = 0; j < 4; j++) s[j]   = (a[j] > 0.f) ? 0x3F80u : ((a[j] < 0.f) ? 0xBF80u : 0u);
  #pragma unroll
  for (int j = 0; j < 4; j++) s[4+j] = (b[j] > 0.f) ? 0x3F80u : ((b[j] < 0.f) ? 0xBF80u : 0u);
  u4 v;
  v.x = (unsigned)s[0] | ((unsigned)s[1] << 16);
  v.y = (unsigned)s[2] | ((unsigned)s[3] << 16);
  v.z = (unsigned)s[4] | ((unsigned)s[5] << 16);
  v.w = (unsigned)s[6] | ((unsigned)s[7] << 16);
  *(u4*)(o + off) = v;
}

// ---------------- GEMM1: split-N with same-XCD pairing ----------------------------------------
// BM=64, BN=128, BK=64, 64 steps; grid 512 = 256 M-tiles x 2 N-halves; 512 thr = 8 waves,
// wave tile 32x32. LDS 48KB (A bf16 dbuf 2x8KB + B dbuf 2x16KB) -> 2 blocks/CU co-resident
// (launch_bounds(512,4)). Remap xcd=d&7, slot=d>>3: pair (gm, nh=0/1) lands 8 dispatch slots
// apart = SAME XCD -> the pair's duplicate A-row reads dedup in that XCD's L2; HBM x-traffic
// stays 268MB. Ledger: per step issue {B(k+1)x2 GL16, A(k+2)}; PACKA(k+1) drains only A(k+1);
// VBAR(1) drains B(k+1), keeps A(k+2). Anti-phase partner block covers every drain.
__global__ __launch_bounds__(512, 4) void gemm1_k(
    const float* __restrict__ x, const unsigned short* __restrict__ w1s,
    const float* __restrict__ b1, unsigned short* __restrict__ h1,
    float* __restrict__ part1s, float* __restrict__ part1q)
{
  __shared__ __align__(16) char lds[49152];   // A: 2x8192 @0 ; B: 2x16384 @16384
  const int tid  = threadIdx.x;
  const int lane = tid & 63;
  const int wid  = tid >> 6;
  const int wm   = wid >> 2;          // 0..1 -> rows wm*32..+31
  const int wn   = wid & 3;           // 0..3 -> local cols wn*32..+31
  const int cl   = lane & 15;
  const int g    = lane >> 4;         // 0..3
  // same-XCD pair mapping
  const int d    = blockIdx.x;
  const int xcd  = d & 7;
  const int slot = d >> 3;
  const int nh   = slot & 1;          // N-half 0/1
  const int gm   = (slot >> 1) * 8 + xcd;   // 0..255
  const int row0 = gm * 64;
  const int col0 = nh * 128;

  // A reg-staging: thread -> row tid>>3 (0..63), 8 contiguous fp32 at (tid&7)*8
  const float* xA = x + (size_t)(row0 + (tid >> 3)) * 4096 + (tid & 7) * 8;
  const int aw = (tid >> 3) * 128 + (((tid & 7) * 16) ^ (((tid >> 3) & 7) << 4));

  // B staging: 2 GL16/thread into 16KB tile [128 n][128B]; linear dest, pre-swizzled src
  const int o0 = tid * 16;
  const int o1 = 8192 + tid * 16;
  const int n0l = o0 >> 7, n1l = o1 >> 7;
  const size_t sB0 = (size_t)(col0 + n0l) * 8192 + ((o0 & 127) ^ ((n0l & 7) << 4));
  const size_t sB1 = (size_t)(col0 + n1l) * 8192 + ((o1 & 127) ^ ((n1l & 7) << 4));

  // hoisted fragment read offsets
  int afo[2][2], bfo[2][2];
  #pragma unroll
  for (int fm = 0; fm < 2; fm++){
    int m = wm * 32 + fm * 16 + cl;
    #pragma unroll
    for (int ks = 0; ks < 2; ks++)
      afo[fm][ks] = m * 128 + ((ks * 64 + g * 16) ^ ((m & 7) << 4));
  }
  #pragma unroll
  for (int fn = 0; fn < 2; fn++){
    int n = wn * 32 + fn * 16 + cl;
    #pragma unroll
    for (int ks = 0; ks < 2; ks++)
      bfo[fn][ks] = n * 128 + ((ks * 64 + g * 16) ^ ((n & 7) << 4));
  }

  f4 acc[2][2];
  const f4 z = {0.f, 0.f, 0.f, 0.f};
  acc[0][0] = z; acc[0][1] = z; acc[1][0] = z; acc[1][1] = z;

  // 2 rotating A reg sets (2 f4 each)
  f4 rA0a, rA0b, rA1a, rA1b;

#define ISSUEA(S, K) do { \
    rA##S##a = *(const f4*)(xA + (size_t)(K) * 64); \
    rA##S##b = *(const f4*)(xA + (size_t)(K) * 64 + 4); \
  } while(0)

#define ISSUEB(BI, K) do { \
    char* _dst = lds + 16384 + (BI) * 16384; \
    GL16((const char*)w1s + sB0 + (size_t)(K) * 128, _dst + o0); \
    GL16((const char*)w1s + sB1 + (size_t)(K) * 128, _dst + o1); \
  } while(0)

#define PACKA(S, AB) do { \
    u4 _v; \
    _v.x = f2bf(rA##S##a[0]) | (f2bf(rA##S##a[1]) << 16); \
    _v.y = f2bf(rA##S##a[2]) | (f2bf(rA##S##a[3]) << 16); \
    _v.z = f2bf(rA##S##b[0]) | (f2bf(rA##S##b[1]) << 16); \
    _v.w = f2bf(rA##S##b[2]) | (f2bf(rA##S##b[3]) << 16); \
    *(u4*)(lds + (AB) * 8192 + aw) = _v; \
  } while(0)

#define COMPUTE(KI) do { \
    const char* _ab = lds + ((KI) & 1) * 8192; \
    const char* _bb = lds + 16384 + ((KI) & 1) * 16384; \
    __builtin_amdgcn_s_setprio(1); \
    { \
      short8 _a0 = *(const short8*)(_ab + afo[0][0]); \
      short8 _a1 = *(const short8*)(_ab + afo[1][0]); \
      short8 _b0 = *(const short8*)(_bb + bfo[0][0]); \
      short8 _b1 = *(const short8*)(_bb + bfo[1][0]); \
      acc[0][0] = __builtin_amdgcn_mfma_f32_16x16x32_bf16(_a0, _b0, acc[0][0], 0, 0, 0); \
      acc[0][1] = __builtin_amdgcn_mfma_f32_16x16x32_bf16(_a0, _b1, acc[0][1], 0, 0, 0); \
      acc[1][0] = __builtin_amdgcn_mfma_f32_16x16x32_bf16(_a1, _b0, acc[1][0], 0, 0, 0); \
      acc[1][1] = __builtin_amdgcn_mfma_f32_16x16x32_bf16(_a1, _b1, acc[1][1], 0, 0, 0); \
    } \
    { \
      short8 _a0 = *(const short8*)(_ab + afo[0][1]); \
      short8 _a1 = *(const short8*)(_ab + afo[1][1]); \
      short8 _b0 = *(const short8*)(_bb + bfo[0][1]); \
      short8 _b1 = *(const short8*)(_bb + bfo[1][1]); \
      acc[0][0] = __builtin_amdgcn_mfma_f32_16x16x32_bf16(_a0, _b0, acc[0][0], 0, 0, 0); \
      acc[0][1] = __builtin_amdgcn_mfma_f32_16x16x32_bf16(_a0, _b1, acc[0][1], 0, 0, 0); \
      acc[1][0] = __builtin_amdgcn_mfma_f32_16x16x32_bf16(_a1, _b0, acc[1][0], 0, 0, 0); \
      acc[1][1] = __builtin_amdgcn_mfma_f32_16x16x32_bf16(_a1, _b1, acc[1][1], 0, 0, 0); \
    } \
    __builtin_amdgcn_s_setprio(0); \
  } while(0)

// step K (0..61): issue B(K+1)->buf (K+1)&1, A(K+2)->set K&1; compute(K);
// PACKA set (K+1)&1 -> abuf (K+1)&1 [compiler drains only A(K+1)]; VBAR(1) keeps A(K+2).
#define STEP(K, SI, SP) do { \
    ISSUEB((K + 1) & 1, (K) + 1); \
    ISSUEA(SI, (K) + 2); \
    SB0; \
    COMPUTE(K); \
    SB0; \
    PACKA(SP, ((K) + 1) & 1); \
    VBAR(1); \
  } while(0)

  // prologue: A(0)->set0 (oldest); B(0)->buf0; A(1)->set1; pack A(0); drain B(0), keep A(1)
  ISSUEA(0, 0);
  ISSUEB(0, 0);
  ISSUEA(1, 1);
  SB0;
  PACKA(0, 0);
  VBAR(1);

  #pragma unroll 1
  for (int k = 0; k < 62; k += 2){
    STEP(k,     0, 1);   // issue A(k+2)->set0; pack A(k+1) from set1
    STEP(k + 1, 1, 0);   // issue A(k+3)->set1; pack A(k+2) from set0
  }
  // step 62: B(63)->buf1; compute(62); pack A(63) from set1; full drain (no A left)
  ISSUEB(1, 63);
  SB0;
  COMPUTE(62);
  SB0;
  PACKA(1, 1);
  VBAR(0);
  // step 63: compute only
  COMPUTE(63);

#undef STEP
#undef COMPUTE
#undef PACKA
#undef ISSUEB
#undef ISSUEA

  // epilogue: bf16 h1 write + fused transposed column stats (per gm,wm partials)
  #pragma unroll
  for (int fn = 0; fn < 2; fn++){
    int c = col0 + wn * 32 + fn * 16 + cl;
    float sb = fsign(b1[c]);
    float s = 0.f, q = 0.f;
    #pragma unroll
    for (int fm = 0; fm < 2; fm++){
      int rbase = row0 + wm * 32 + fm * 16 + g * 4;
      #pragma unroll
      for (int i = 0; i < 4; i++){
        float v = acc[fm][fn][i] + sb;
        h1[(size_t)(rbase + i) * 256 + c] = (unsigned short)f2bf(v);
        s += v; q += v * v;
      }
    }
    s += __shfl_xor(s, 16, 64); s += __shfl_xor(s, 32, 64);
    q += __shfl_xor(q, 16, 64); q += __shfl_xor(q, 32, 64);
    if (g == 0){
      part1s[(size_t)c * 512 + gm * 2 + wm] = s;
      part1q[(size_t)c * 512 + gm * 2 + wm] = q;
    }
  }
}

// ---------------- BN params from transposed partials ------------------------------------------
template<int COLS, int NBLK>
__global__ __launch_bounds__(64) void params_k(
    const float* __restrict__ ps, const float* __restrict__ pq,
    const float* __restrict__ g, const float* __restrict__ be,
    float* __restrict__ ab){
  int j = blockIdx.x * 64 + threadIdx.x;
  const f4* vs = (const f4*)(ps + (size_t)j * NBLK);
  const f4* vq = (const f4*)(pq + (size_t)j * NBLK);
  f4 s4 = {0,0,0,0}, q4 = {0,0,0,0};
  #pragma unroll 8
  for (int b = 0; b < NBLK/4; b++){ s4 += vs[b]; q4 += vq[b]; }
  float s = s4[0]+s4[1]+s4[2]+s4[3];
  float q = q4[0]+q4[1]+q4[2]+q4[3];
  float mu  = s * (1.f/16384.f);
  float var = q * (1.f/16384.f) - mu*mu;
  float a   = g[j] * rsqrtf(var + 1e-5f);
  ab[j] = a;
  ab[COLS + j] = be[j] - mu*a;
}

// ---------------- GEMM2: h2(bf16) = clip(BN1(h1)) @ signW2^T + sign(b2), fused stats -----------
__global__ __launch_bounds__(512) void gemm2_k(
    const unsigned short* __restrict__ h1, const unsigned short* __restrict__ w2s,
    const float* __restrict__ b2, const float* __restrict__ ab1,
    unsigned short* __restrict__ h2, float* __restrict__ part2s, float* __restrict__ part2q)
{
  __shared__ __align__(16) char lds[32768];
  __shared__ __align__(16) float a1l[256];
  __shared__ __align__(16) float c1l[256];
  const int tid  = threadIdx.x;
  const int lane = tid & 63;
  const int wid  = tid >> 6;          // 0..7 -> cols wid*16..+15
  const int cl   = lane & 15;
  const int g    = lane >> 4;
  const int klo  = g * 8;
  const int row0 = blockIdx.x * 64;

  if (tid < 256) a1l[tid] = ab1[tid];
  else           c1l[tid - 256] = ab1[tid];

  const int am  = tid >> 3;
  const int ak0 = (tid & 7) * 8;
  const unsigned short* hA = h1 + (size_t)(row0 + am) * 256 + ak0;
  const int aw = ((am * 128) + (ak0 * 2)) ^ ((am & 7) << 4);
  const unsigned short* wbase = w2s + (size_t)(wid * 16 + cl) * 256 + klo;

  u4 q0 = *(const u4*)(hA);
  u4 q1 = *(const u4*)(hA + 64);
  u4 q2 = *(const u4*)(hA + 128);
  u4 q3 = *(const u4*)(hA + 192);
  short8 Bq0, Bq1, Br0, Br1;
  Bq0 = *(const short8*)(wbase);
  Bq1 = *(const short8*)(wbase + 32);

  BARRIER();                 // a1l/c1l visible

#define TRW(KB, RAW) do { \
    f4 _a0 = *(const f4*)(&a1l[(KB)*64 + ak0]); \
    f4 _a1 = *(const f4*)(&a1l[(KB)*64 + ak0 + 4]); \
    f4 _c0 = *(const f4*)(&c1l[(KB)*64 + ak0]); \
    f4 _c1 = *(const f4*)(&c1l[(KB)*64 + ak0 + 4]); \
    float _t0 = hclip(_a0[0]*bflo(RAW.x) + _c0[0]); \
    float _t1 = hclip(_a0[1]*bfhi(RAW.x) + _c0[1]); \
    float _t2 = hclip(_a0[2]*bflo(RAW.y) + _c0[2]); \
    float _t3 = hclip(_a0[3]*bfhi(RAW.y) + _c0[3]); \
    float _t4 = hclip(_a1[0]*bflo(RAW.z) + _c1[0]); \
    float _t5 = hclip(_a1[1]*bfhi(RAW.z) + _c1[1]); \
    float _t6 = hclip(_a1[2]*bflo(RAW.w) + _c1[2]); \
    float _t7 = hclip(_a1[3]*bfhi(RAW.w) + _c1[3]); \
    u4 _v; \
    _v.x = f2bf(_t0) | (f2bf(_t1) << 16); \
    _v.y = f2bf(_t2) | (f2bf(_t3) << 16); \
    _v.z = f2bf(_t4) | (f2bf(_t5) << 16); \
    _v.w = f2bf(_t6) | (f2bf(_t7) << 16); \
    *(u4*)(lds + (KB)*8192 + aw) = _v; \
  } while(0)

  TRW(0, q0); TRW(1, q1); TRW(2, q2); TRW(3, q3);
#undef TRW
  BARRIER();

  f4 acc[4];
  const f4 z = {0.f, 0.f, 0.f, 0.f};
  #pragma unroll
  for (int i = 0; i < 4; i++) acc[i] = z;

#define LOADB2(P, KB) do { \
    B##P##0 = *(const short8*)(wbase + (KB)*64); \
    B##P##1 = *(const short8*)(wbase + (KB)*64 + 32); \
  } while(0)

#define COMP2(BASE, P) do { \
    const char* _ab = (const char*)(BASE); \
    short8 _af[4][2]; \
    _Pragma("unroll") \
    for (int fm = 0; fm < 4; fm++){ \
      int _m = fm*16 + cl; \
      _af[fm][0] = *(const short8*)(_ab + ((_m*128 + klo*2) ^ ((_m & 7) << 4))); \
      _af[fm][1] = *(const short8*)(_ab + ((_m*128 + (32 + klo)*2) ^ ((_m & 7) << 4))); \
    } \
    _Pragma("unroll") \
    for (int fm = 0; fm < 4; fm++){ \
      acc[fm] = __builtin_amdgcn_mfma_f32_16x16x32_bf16(_af[fm][0], B##P##0, acc[fm], 0, 0, 0); \
      acc[fm] = __builtin_amdgcn_mfma_f32_16x16x32_bf16(_af[fm][1], B##P##1, acc[fm], 0, 0, 0); \
    } \
  } while(0)

  LOADB2(r, 1);
  COMP2(lds,         q);
  LOADB2(q, 2);
  COMP2(lds +  8192, r);
  LOADB2(r, 3);
  COMP2(lds + 16384, q);
  COMP2(lds + 24576, r);
#undef COMP2
#undef LOADB2

  {
    int c = wid*16 + cl;
    float sb = fsign(b2[c]);
    float s = 0.f, q = 0.f;
    #pragma unroll
    for (int fm = 0; fm < 4; fm++){
      int rbase = row0 + fm*16 + g*4;
      #pragma unroll
      for (int i = 0; i < 4; i++){
        float v = acc[fm][i] + sb;
        h2[(size_t)(rbase + i)*128 + c] = (unsigned short)f2bf(v);
        s += v; q += v*v;
      }
    }
    s += __shfl_xor(s, 16, 64); s += __shfl_xor(s, 32, 64);
    q += __shfl_xor(q, 16, 64); q += __shfl_xor(q, 32, 64);
    if (g == 0){
      part2s[c*256 + blockIdx.x] = s;
      part2q[c*256 + blockIdx.x] = q;
    }
  }
}

// ---------------- final: out = clip(BN2(h2)) @ W4^T + b4, BN2 params fused ---------------------
__global__ __launch_bounds__(128) void final_k(
    const unsigned short* __restrict__ h2,
    const float* __restrict__ part2s, const float* __restrict__ part2q,
    const float* __restrict__ g2, const float* __restrict__ be2,
    const float* __restrict__ W4, const float* __restrict__ b4,
    float* __restrict__ out)
{
  __shared__ __align__(16) float W4l[12*128];
  __shared__ __align__(16) float a2l[128];
  __shared__ __align__(16) float c2l[128];
  const int t = threadIdx.x;
  #pragma unroll
  for (int i = 0; i < 3; i++)
    *(f4*)&W4l[(i*128 + t)*4] = *(const f4*)(W4 + (i*128 + t)*4);
  {
    const f4* vs = (const f4*)(part2s + t*256);
    const f4* vq = (const f4*)(part2q + t*256);
    f4 s4 = {0,0,0,0}, q4 = {0,0,0,0};
    #pragma unroll 8
    for (int b = 0; b < 64; b++){ s4 += vs[b]; q4 += vq[b]; }
    float s = s4[0]+s4[1]+s4[2]+s4[3];
    float q = q4[0]+q4[1]+q4[2]+q4[3];
    float mu  = s * (1.f/16384.f);
    float var = q * (1.f/16384.f) - mu*mu;
    float a   = g2[t] * rsqrtf(var + 1e-5f);
    a2l[t] = a;
    c2l[t] = be2[t] - mu*a;
  }
  __syncthreads();

  const int r = blockIdx.x * 128 + t;
  const u4* hp = (const u4*)(h2 + (size_t)r * 128);
  u4 hv0 = hp[0], hv1 = hp[1], hv2 = hp[2],  hv3 = hp[3];
  u4 hv4 = hp[4], hv5 = hp[5], hv6 = hp[6],  hv7 = hp[7];
  u4 hv8 = hp[8], hv9 = hp[9], hv10 = hp[10], hv11 = hp[11];
  u4 hv12 = hp[12], hv13 = hp[13], hv14 = hp[14], hv15 = hp[15];

  float acc[12];
  #pragma unroll
  for (int o = 0; o < 12; o++) acc[o] = b4[o];

#define FPROC(HV, J) do { \
    f4 a0 = *(const f4*)&a2l[(J)*8];     f4 a1 = *(const f4*)&a2l[(J)*8 + 4]; \
    f4 c0 = *(const f4*)&c2l[(J)*8];     f4 c1 = *(const f4*)&c2l[(J)*8 + 4]; \
    float tt0 = hclip(a0[0]*bflo(HV.x) + c0[0]); \
    float tt1 = hclip(a0[1]*bfhi(HV.x) + c0[1]); \
    float tt2 = hclip(a0[2]*bflo(HV.y) + c0[2]); \
    float tt3 = hclip(a0[3]*bfhi(HV.y) + c0[3]); \
    float tt4 = hclip(a1[0]*bflo(HV.z) + c1[0]); \
    float tt5 = hclip(a1[1]*bfhi(HV.z) + c1[1]); \
    float tt6 = hclip(a1[2]*bflo(HV.w) + c1[2]); \
    float tt7 = hclip(a1[3]*bfhi(HV.w) + c1[3]); \
    _Pragma("unroll") \
    for (int o = 0; o < 12; o++){ \
      f4 w0 = *(const f4*)&W4l[o*128 + (J)*8]; \
      f4 w1 = *(const f4*)&W4l[o*128 + (J)*8 + 4]; \
      acc[o] += tt0*w0[0] + tt1*w0[1] + tt2*w0[2] + tt3*w0[3] \
              + tt4*w1[0] + tt5*w1[1] + tt6*w1[2] + tt7*w1[3]; \
    } \
  } while(0)

  FPROC(hv0, 0);  FPROC(hv1, 1);  FPROC(hv2, 2);   FPROC(hv3, 3);
  FPROC(hv4, 4);  FPROC(hv5, 5);  FPROC(hv6, 6);   FPROC(hv7, 7);
  FPROC(hv8, 8);  FPROC(hv9, 9);  FPROC(hv10, 10); FPROC(hv11, 11);
  FPROC(hv12, 12); FPROC(hv13, 13); FPROC(hv14, 14); FPROC(hv15, 15);
#undef FPROC

  #pragma unroll
  for (int o = 0; o < 12; o++) out[(size_t)r*12 + o] = acc[o];
}

// ---------------- launch ----------------
extern "C" void kernel_launch(void* const* d_in, const int* in_sizes, int n_in,
                              void* d_out, int out_size, void* d_ws, size_t ws_size,
                              hipStream_t stream)
{
  const float* x   = (const float*)d_in[0];
  const float* W1  = (const float*)d_in[1];
  const float* b1  = (const float*)d_in[2];
  const float* g1  = (const float*)d_in[3];
  const float* be1 = (const float*)d_in[4];
  const float* W2  = (const float*)d_in[5];
  const float* b2  = (const float*)d_in[6];
  const float* g2  = (const float*)d_in[7];
  const float* be2 = (const float*)d_in[8];
  const float* W4  = (const float*)d_in[9];
  const float* b4  = (const float*)d_in[10];
  float* out = (float*)d_out;

  char* ws = (char*)d_ws;
  unsigned short* h1     = (unsigned short*)(ws);              //  8 MB  [16384,256] bf16
  unsigned short* h2     = (unsigned short*)(ws + 8388608);    //  4 MB  [16384,128] bf16
  unsigned short* w1s    = (unsigned short*)(ws + 12582912);   //  2 MB  [256,4096] bf16
  unsigned short* w2s    = (unsigned short*)(ws + 14680064);   // 64 KB  [128,256] bf16
  float*          part1s = (float*)(ws + 14745600);            // 512 KB [256][512]
  float*          part1q = (float*)(ws + 15269888);            // 512 KB
  float*          part2s = (float*)(ws + 15794176);            // 128 KB [128][256]
  float*          part2q = (float*)(ws + 15925248);            // 128 KB
  float*          ab1    = (float*)(ws + 16056320);            // a1[256], c1[256]

  prep_sign_k<<<528, 256, 0, stream>>>(W1, w1s, W2, w2s);
  gemm1_k<<<512, 512, 0, stream>>>(x, w1s, b1, h1, part1s, part1q);
  params_k<256, 512><<<4, 64, 0, stream>>>(part1s, part1q, g1, be1, ab1);
  gemm2_k<<<256, 512, 0, stream>>>(h1, w2s, b2, ab1, h2, part2s, part2q);
  final_k<<<128, 128, 0, stream>>>(h2, part2s, part2q, g2, be2, W4, b4, out);
}

// Round 20
// 119.815 us; speedup vs baseline: 1.9370x; 1.0491x over previous
//
#include <hip/hip_runtime.h>
#include <cstddef>

typedef __attribute__((ext_vector_type(8))) short short8;
typedef __attribute__((ext_vector_type(4))) float f4;
typedef __attribute__((ext_vector_type(4))) unsigned int u4;

__device__ __forceinline__ unsigned int f2bf(float f){
  unsigned int u = __float_as_uint(f);
  u += 0x7fffu + ((u >> 16) & 1u);   // RNE to bf16
  return u >> 16;
}
__device__ __forceinline__ float bflo(unsigned int w){ return __uint_as_float((w & 0xFFFFu) << 16); }
__device__ __forceinline__ float bfhi(unsigned int w){ return __uint_as_float(w & 0xFFFF0000u); }
__device__ __forceinline__ float fsign(float x){ return (x > 0.f) ? 1.f : ((x < 0.f) ? -1.f : 0.f); }
__device__ __forceinline__ float hclip(float x){ return fminf(1.f, fmaxf(-1.f, x)); }

#define SB0 __builtin_amdgcn_sched_barrier(0)

// lgkm-only barrier (vmem loads stay in flight)
#define BARRIER() do { \
    SB0; \
    asm volatile("s_waitcnt lgkmcnt(0)" ::: "memory"); \
    __builtin_amdgcn_s_barrier(); \
    asm volatile("" ::: "memory"); \
    SB0; \
  } while(0)

// counted-vmcnt barrier: drain all but N newest vmem ops, then workgroup barrier
#define VBAR(N) do { \
    SB0; \
    asm volatile("s_waitcnt vmcnt(" #N ") lgkmcnt(0)" ::: "memory"); \
    __builtin_amdgcn_s_barrier(); \
    asm volatile("" ::: "memory"); \
    SB0; \
  } while(0)

// global -> LDS direct DMA, 16B per lane
#define GL16(gp, lp) __builtin_amdgcn_global_load_lds( \
    (const __attribute__((address_space(1))) void*)(gp), \
    (__attribute__((address_space(3))) void*)(lp), 16, 0, 0)

// ---------------- prep: sign(W1)+sign(W2) fp32 -> bf16 {+1,-1,0}, one dispatch ----------------
__global__ void prep_sign_k(const float* __restrict__ W1, unsigned short* __restrict__ w1s,
                            const float* __restrict__ W2, unsigned short* __restrict__ w2s){
  int i = (blockIdx.x * blockDim.x + threadIdx.x) * 8;
  const float* w; unsigned short* o; int off;
  if (i < 1048576){ w = W1; o = w1s; off = i; }
  else            { w = W2; o = w2s; off = i - 1048576; if (off >= 32768) return; }
  f4 a = *(const f4*)(w + off);
  f4 b = *(const f4*)(w + off + 4);
  unsigned short s[8];
  #pragma unroll
  for (int j = 0; j < 4; j++) s[j]   = (a[j] > 0.f) ? 0x3F80u : ((a[j] < 0.f) ? 0xBF80u : 0u);
  #pragma unroll
  for (int j = 0; j < 4; j++) s[4+j] = (b[j] > 0.f) ? 0x3F80u : ((b[j] < 0.f) ? 0xBF80u : 0u);
  u4 v;
  v.x = (unsigned)s[0] | ((unsigned)s[1] << 16);
  v.y = (unsigned)s[2] | ((unsigned)s[3] << 16);
  v.z = (unsigned)s[4] | ((unsigned)s[5] << 16);
  v.w = (unsigned)s[6] | ((unsigned)s[7] << 16);
  *(u4*)(o + off) = v;
}

// ---------------- GEMM1: h1(bf16) = x @ signW1^T + sign(b1), fused transposed col-stats ---------
// BM=64, BN=256, BK=64, 64 K-steps. 512 thr = 8 waves, wave tile 32x64.
// A: reg-stage fp32 (depth-4 rotating sets) -> f2bf ONCE -> b128 ds_write into bf16
//    abuf 2x8KB (XOR (m&7)<<4, conflict-free). B: GL16 depth-3 into 4x32KB bufs.
// Per step k: issue B(k+3) THEN A(k+4); COMPUTE(k); PACKA(k+1) [compiler wait ~no-op,
// A 3 steps old]; VBAR(14) drains exactly batch@k-2 -> A-slack 3 steps, B-slack 3 steps,
// ~96-144KB in flight across every barrier.
__global__ __launch_bounds__(512, 1) void gemm1_k(
    const float* __restrict__ x, const unsigned short* __restrict__ w1s,
    const float* __restrict__ b1, unsigned short* __restrict__ h1,
    float* __restrict__ part1s, float* __restrict__ part1q)
{
  __shared__ __align__(16) char lds[147456];   // A: 2x8KB @0 ; B: 4x32KB @16384
  const int tid  = threadIdx.x;
  const int lane = tid & 63;
  const int wid  = tid >> 6;
  const int wm   = wid >> 2;          // 0..1 -> rows wm*32..+31
  const int wn   = wid & 3;           // 0..3 -> cols wn*64..+63
  const int cl   = lane & 15;
  const int g    = lane >> 4;         // 0..3
  const int row0 = blockIdx.x * 64;

  // A reg-staging: thread -> row tid>>3 (0..63), 8 contiguous fp32 at (tid&7)*8
  const float* xA = x + (size_t)(row0 + (tid >> 3)) * 4096 + (tid & 7) * 8;
  const int aw = (tid >> 3) * 128 + (((tid & 7) * 16) ^ (((tid >> 3) & 7) << 4));

  // hoisted fragment read offsets
  int afo[2][2], bfo[4][2];
  #pragma unroll
  for (int fm = 0; fm < 2; fm++){
    int m = wm * 32 + fm * 16 + cl;
    #pragma unroll
    for (int ks = 0; ks < 2; ks++)
      afo[fm][ks] = m * 128 + ((ks * 64 + g * 16) ^ ((m & 7) << 4));
  }
  #pragma unroll
  for (int fn = 0; fn < 4; fn++){
    int n = wn * 64 + fn * 16 + cl;
    #pragma unroll
    for (int ks = 0; ks < 2; ks++)
      bfo[fn][ks] = n * 128 + ((ks * 64 + g * 16) ^ ((n & 7) << 4));
  }

  f4 acc[2][4];
  const f4 z = {0.f, 0.f, 0.f, 0.f};
  #pragma unroll
  for (int i = 0; i < 2; i++)
    #pragma unroll
    for (int j = 0; j < 4; j++) acc[i][j] = z;

  // 4 rotating A reg sets (2 f4 each)
  f4 rA0a, rA0b, rA1a, rA1b, rA2a, rA2b, rA3a, rA3b;

#define ISSUEA(S, K) do { \
    rA##S##a = *(const f4*)(xA + (size_t)(K) * 64); \
    rA##S##b = *(const f4*)(xA + (size_t)(K) * 64 + 4); \
  } while(0)

#define ISSUEB(BI, K) do { \
    char* _dst = lds + 16384 + (BI) * 32768; \
    _Pragma("unroll") \
    for (int _c = 0; _c < 4; _c++){ \
      int _o  = _c * 8192 + tid * 16; \
      int _n  = _o >> 7; \
      int _kb = (_o & 127) ^ ((_n & 7) << 4); \
      GL16((const char*)w1s + (size_t)_n * 8192 + (size_t)(K) * 128 + _kb, _dst + _o); \
    } } while(0)

#define PACKA(S, AB) do { \
    u4 _v; \
    _v.x = f2bf(rA##S##a[0]) | (f2bf(rA##S##a[1]) << 16); \
    _v.y = f2bf(rA##S##a[2]) | (f2bf(rA##S##a[3]) << 16); \
    _v.z = f2bf(rA##S##b[0]) | (f2bf(rA##S##b[1]) << 16); \
    _v.w = f2bf(rA##S##b[2]) | (f2bf(rA##S##b[3]) << 16); \
    *(u4*)(lds + (AB) * 8192 + aw) = _v; \
  } while(0)

#define COMPUTE(KI) do { \
    const char* _ab = lds + ((KI) & 1) * 8192; \
    const char* _bb = lds + 16384 + ((KI) & 3) * 32768; \
    short8 _af[2][2]; short8 _bf[4][2]; \
    _Pragma("unroll") \
    for (int _fm = 0; _fm < 2; _fm++) \
      _Pragma("unroll") \
      for (int _ks = 0; _ks < 2; _ks++) \
        _af[_fm][_ks] = *(const short8*)(_ab + afo[_fm][_ks]); \
    _Pragma("unroll") \
    for (int _fn = 0; _fn < 4; _fn++) \
      _Pragma("unroll") \
      for (int _ks = 0; _ks < 2; _ks++) \
        _bf[_fn][_ks] = *(const short8*)(_bb + bfo[_fn][_ks]); \
    __builtin_amdgcn_s_setprio(1); \
    _Pragma("unroll") \
    for (int _ks = 0; _ks < 2; _ks++) \
      _Pragma("unroll") \
      for (int _fm = 0; _fm < 2; _fm++) \
        _Pragma("unroll") \
        for (int _fn = 0; _fn < 4; _fn++) \
          acc[_fm][_fn] = __builtin_amdgcn_mfma_f32_16x16x32_bf16(_af[_fm][_ks], _bf[_fn][_ks], acc[_fm][_fn], 0, 0, 0); \
    __builtin_amdgcn_s_setprio(0); \
  } while(0)

#define STEP(K, AS, AP) do { \
    int _kb3 = (K) + 3; if (_kb3 > 63) _kb3 = 63; \
    int _ka4 = (K) + 4; if (_ka4 > 63) _ka4 = 63; \
    ISSUEB((K + 3) & 3, _kb3); \
    ISSUEA(AS, _ka4); \
    SB0; \
    COMPUTE(K); \
    SB0; \
    if ((K) < 63) PACKA(AP, ((K) + 1) & 1); \
    VBAR(14); \
  } while(0)

  // prologue: A(0) first (so PACKA(0) drains only it), then B(0..2), A(1..3)
  ISSUEA(0, 0);
  ISSUEB(0, 0); ISSUEB(1, 1); ISSUEB(2, 2);
  ISSUEA(1, 1); ISSUEA(2, 2); ISSUEA(3, 3);
  SB0;
  PACKA(0, 0);          // waits A(0) only (oldest)
  VBAR(14);             // drains B(0); keeps B(1),B(2),A(1..3)=14

  #pragma unroll 1
  for (int kk = 0; kk < 64; kk += 4){
    STEP(kk + 0, 0, 1);
    STEP(kk + 1, 1, 2);
    STEP(kk + 2, 2, 3);
    STEP(kk + 3, 3, 0);
  }
  asm volatile("s_waitcnt vmcnt(0)" ::: "memory");

#undef STEP
#undef COMPUTE
#undef PACKA
#undef ISSUEB
#undef ISSUEA

  // epilogue: bf16 h1 write + fused transposed column stats (per block,wm partials)
  #pragma unroll
  for (int fn = 0; fn < 4; fn++){
    int c = wn * 64 + fn * 16 + cl;
    float sb = fsign(b1[c]);
    float s = 0.f, q = 0.f;
    #pragma unroll
    for (int fm = 0; fm < 2; fm++){
      int rbase = row0 + wm * 32 + fm * 16 + g * 4;
      #pragma unroll
      for (int i = 0; i < 4; i++){
        float v = acc[fm][fn][i] + sb;
        h1[(size_t)(rbase + i) * 256 + c] = (unsigned short)f2bf(v);
        s += v; q += v * v;
      }
    }
    s += __shfl_xor(s, 16, 64); s += __shfl_xor(s, 32, 64);
    q += __shfl_xor(q, 16, 64); q += __shfl_xor(q, 32, 64);
    if (g == 0){
      part1s[(size_t)c * 512 + blockIdx.x * 2 + wm] = s;
      part1q[(size_t)c * 512 + blockIdx.x * 2 + wm] = q;
    }
  }
}

// ---------------- BN params from transposed partials ------------------------------------------
template<int COLS, int NBLK>
__global__ __launch_bounds__(64) void params_k(
    const float* __restrict__ ps, const float* __restrict__ pq,
    const float* __restrict__ g, const float* __restrict__ be,
    float* __restrict__ ab){
  int j = blockIdx.x * 64 + threadIdx.x;
  const f4* vs = (const f4*)(ps + (size_t)j * NBLK);
  const f4* vq = (const f4*)(pq + (size_t)j * NBLK);
  f4 s4 = {0,0,0,0}, q4 = {0,0,0,0};
  #pragma unroll 8
  for (int b = 0; b < NBLK/4; b++){ s4 += vs[b]; q4 += vq[b]; }
  float s = s4[0]+s4[1]+s4[2]+s4[3];
  float q = q4[0]+q4[1]+q4[2]+q4[3];
  float mu  = s * (1.f/16384.f);
  float var = q * (1.f/16384.f) - mu*mu;
  float a   = g[j] * rsqrtf(var + 1e-5f);
  ab[j] = a;
  ab[COLS + j] = be[j] - mu*a;
}

// ---------------- GEMM2: h2(bf16) = clip(BN1(h1)) @ signW2^T + sign(b2), fused stats -----------
__global__ __launch_bounds__(512) void gemm2_k(
    const unsigned short* __restrict__ h1, const unsigned short* __restrict__ w2s,
    const float* __restrict__ b2, const float* __restrict__ ab1,
    unsigned short* __restrict__ h2, float* __restrict__ part2s, float* __restrict__ part2q)
{
  __shared__ __align__(16) char lds[32768];
  __shared__ __align__(16) float a1l[256];
  __shared__ __align__(16) float c1l[256];
  const int tid  = threadIdx.x;
  const int lane = tid & 63;
  const int wid  = tid >> 6;          // 0..7 -> cols wid*16..+15
  const int cl   = lane & 15;
  const int g    = lane >> 4;
  const int klo  = g * 8;
  const int row0 = blockIdx.x * 64;

  if (tid < 256) a1l[tid] = ab1[tid];
  else           c1l[tid - 256] = ab1[tid];

  const int am  = tid >> 3;
  const int ak0 = (tid & 7) * 8;
  const unsigned short* hA = h1 + (size_t)(row0 + am) * 256 + ak0;
  const int aw = ((am * 128) + (ak0 * 2)) ^ ((am & 7) << 4);
  const unsigned short* wbase = w2s + (size_t)(wid * 16 + cl) * 256 + klo;

  u4 q0 = *(const u4*)(hA);
  u4 q1 = *(const u4*)(hA + 64);
  u4 q2 = *(const u4*)(hA + 128);
  u4 q3 = *(const u4*)(hA + 192);
  short8 Bq0, Bq1, Br0, Br1;
  Bq0 = *(const short8*)(wbase);
  Bq1 = *(const short8*)(wbase + 32);

  BARRIER();                 // a1l/c1l visible

#define TRW(KB, RAW) do { \
    f4 _a0 = *(const f4*)(&a1l[(KB)*64 + ak0]); \
    f4 _a1 = *(const f4*)(&a1l[(KB)*64 + ak0 + 4]); \
    f4 _c0 = *(const f4*)(&c1l[(KB)*64 + ak0]); \
    f4 _c1 = *(const f4*)(&c1l[(KB)*64 + ak0 + 4]); \
    float _t0 = hclip(_a0[0]*bflo(RAW.x) + _c0[0]); \
    float _t1 = hclip(_a0[1]*bfhi(RAW.x) + _c0[1]); \
    float _t2 = hclip(_a0[2]*bflo(RAW.y) + _c0[2]); \
    float _t3 = hclip(_a0[3]*bfhi(RAW.y) + _c0[3]); \
    float _t4 = hclip(_a1[0]*bflo(RAW.z) + _c1[0]); \
    float _t5 = hclip(_a1[1]*bfhi(RAW.z) + _c1[1]); \
    float _t6 = hclip(_a1[2]*bflo(RAW.w) + _c1[2]); \
    float _t7 = hclip(_a1[3]*bfhi(RAW.w) + _c1[3]); \
    u4 _v; \
    _v.x = f2bf(_t0) | (f2bf(_t1) << 16); \
    _v.y = f2bf(_t2) | (f2bf(_t3) << 16); \
    _v.z = f2bf(_t4) | (f2bf(_t5) << 16); \
    _v.w = f2bf(_t6) | (f2bf(_t7) << 16); \
    *(u4*)(lds + (KB)*8192 + aw) = _v; \
  } while(0)

  TRW(0, q0); TRW(1, q1); TRW(2, q2); TRW(3, q3);
#undef TRW
  BARRIER();

  f4 acc[4];
  const f4 z = {0.f, 0.f, 0.f, 0.f};
  #pragma unroll
  for (int i = 0; i < 4; i++) acc[i] = z;

#define LOADB2(P, KB) do { \
    B##P##0 = *(const short8*)(wbase + (KB)*64); \
    B##P##1 = *(const short8*)(wbase + (KB)*64 + 32); \
  } while(0)

#define COMP2(BASE, P) do { \
    const char* _ab = (const char*)(BASE); \
    short8 _af[4][2]; \
    _Pragma("unroll") \
    for (int fm = 0; fm < 4; fm++){ \
      int _m = fm*16 + cl; \
      _af[fm][0] = *(const short8*)(_ab + ((_m*128 + klo*2) ^ ((_m & 7) << 4))); \
      _af[fm][1] = *(const short8*)(_ab + ((_m*128 + (32 + klo)*2) ^ ((_m & 7) << 4))); \
    } \
    _Pragma("unroll") \
    for (int fm = 0; fm < 4; fm++){ \
      acc[fm] = __builtin_amdgcn_mfma_f32_16x16x32_bf16(_af[fm][0], B##P##0, acc[fm], 0, 0, 0); \
      acc[fm] = __builtin_amdgcn_mfma_f32_16x16x32_bf16(_af[fm][1], B##P##1, acc[fm], 0, 0, 0); \
    } \
  } while(0)

  LOADB2(r, 1);
  COMP2(lds,         q);
  LOADB2(q, 2);
  COMP2(lds +  8192, r);
  LOADB2(r, 3);
  COMP2(lds + 16384, q);
  COMP2(lds + 24576, r);
#undef COMP2
#undef LOADB2

  {
    int c = wid*16 + cl;
    float sb = fsign(b2[c]);
    float s = 0.f, q = 0.f;
    #pragma unroll
    for (int fm = 0; fm < 4; fm++){
      int rbase = row0 + fm*16 + g*4;
      #pragma unroll
      for (int i = 0; i < 4; i++){
        float v = acc[fm][i] + sb;
        h2[(size_t)(rbase + i)*128 + c] = (unsigned short)f2bf(v);
        s += v; q += v*v;
      }
    }
    s += __shfl_xor(s, 16, 64); s += __shfl_xor(s, 32, 64);
    q += __shfl_xor(q, 16, 64); q += __shfl_xor(q, 32, 64);
    if (g == 0){
      part2s[c*256 + blockIdx.x] = s;
      part2q[c*256 + blockIdx.x] = q;
    }
  }
}

// ---------------- final: out = clip(BN2(h2)) @ W4^T + b4, BN2 params fused ---------------------
__global__ __launch_bounds__(128) void final_k(
    const unsigned short* __restrict__ h2,
    const float* __restrict__ part2s, const float* __restrict__ part2q,
    const float* __restrict__ g2, const float* __restrict__ be2,
    const float* __restrict__ W4, const float* __restrict__ b4,
    float* __restrict__ out)
{
  __shared__ __align__(16) float W4l[12*128];
  __shared__ __align__(16) float a2l[128];
  __shared__ __align__(16) float c2l[128];
  const int t = threadIdx.x;
  #pragma unroll
  for (int i = 0; i < 3; i++)
    *(f4*)&W4l[(i*128 + t)*4] = *(const f4*)(W4 + (i*128 + t)*4);
  {
    const f4* vs = (const f4*)(part2s + t*256);
    const f4* vq = (const f4*)(part2q + t*256);
    f4 s4 = {0,0,0,0}, q4 = {0,0,0,0};
    #pragma unroll 8
    for (int b = 0; b < 64; b++){ s4 += vs[b]; q4 += vq[b]; }
    float s = s4[0]+s4[1]+s4[2]+s4[3];
    float q = q4[0]+q4[1]+q4[2]+q4[3];
    float mu  = s * (1.f/16384.f);
    float var = q * (1.f/16384.f) - mu*mu;
    float a   = g2[t] * rsqrtf(var + 1e-5f);
    a2l[t] = a;
    c2l[t] = be2[t] - mu*a;
  }
  __syncthreads();

  const int r = blockIdx.x * 128 + t;
  const u4* hp = (const u4*)(h2 + (size_t)r * 128);
  u4 hv0 = hp[0], hv1 = hp[1], hv2 = hp[2],  hv3 = hp[3];
  u4 hv4 = hp[4], hv5 = hp[5], hv6 = hp[6],  hv7 = hp[7];
  u4 hv8 = hp[8], hv9 = hp[9], hv10 = hp[10], hv11 = hp[11];
  u4 hv12 = hp[12], hv13 = hp[13], hv14 = hp[14], hv15 = hp[15];

  float acc[12];
  #pragma unroll
  for (int o = 0; o < 12; o++) acc[o] = b4[o];

#define FPROC(HV, J) do { \
    f4 a0 = *(const f4*)&a2l[(J)*8];     f4 a1 = *(const f4*)&a2l[(J)*8 + 4]; \
    f4 c0 = *(const f4*)&c2l[(J)*8];     f4 c1 = *(const f4*)&c2l[(J)*8 + 4]; \
    float tt0 = hclip(a0[0]*bflo(HV.x) + c0[0]); \
    float tt1 = hclip(a0[1]*bfhi(HV.x) + c0[1]); \
    float tt2 = hclip(a0[2]*bflo(HV.y) + c0[2]); \
    float tt3 = hclip(a0[3]*bfhi(HV.y) + c0[3]); \
    float tt4 = hclip(a1[0]*bflo(HV.z) + c1[0]); \
    float tt5 = hclip(a1[1]*bfhi(HV.z) + c1[1]); \
    float tt6 = hclip(a1[2]*bflo(HV.w) + c1[2]); \
    float tt7 = hclip(a1[3]*bfhi(HV.w) + c1[3]); \
    _Pragma("unroll") \
    for (int o = 0; o < 12; o++){ \
      f4 w0 = *(const f4*)&W4l[o*128 + (J)*8]; \
      f4 w1 = *(const f4*)&W4l[o*128 + (J)*8 + 4]; \
      acc[o] += tt0*w0[0] + tt1*w0[1] + tt2*w0[2] + tt3*w0[3] \
              + tt4*w1[0] + tt5*w1[1] + tt6*w1[2] + tt7*w1[3]; \
    } \
  } while(0)

  FPROC(hv0, 0);  FPROC(hv1, 1);  FPROC(hv2, 2);   FPROC(hv3, 3);
  FPROC(hv4, 4);  FPROC(hv5, 5);  FPROC(hv6, 6);   FPROC(hv7, 7);
  FPROC(hv8, 8);  FPROC(hv9, 9);  FPROC(hv10, 10); FPROC(hv11, 11);
  FPROC(hv12, 12); FPROC(hv13, 13); FPROC(hv14, 14); FPROC(hv15, 15);
#undef FPROC

  #pragma unroll
  for (int o = 0; o < 12; o++) out[(size_t)r*12 + o] = acc[o];
}

// ---------------- launch ----------------
extern "C" void kernel_launch(void* const* d_in, const int* in_sizes, int n_in,
                              void* d_out, int out_size, void* d_ws, size_t ws_size,
                              hipStream_t stream)
{
  const float* x   = (const float*)d_in[0];
  const float* W1  = (const float*)d_in[1];
  const float* b1  = (const float*)d_in[2];
  const float* g1  = (const float*)d_in[3];
  const float* be1 = (const float*)d_in[4];
  const float* W2  = (const float*)d_in[5];
  const float* b2  = (const float*)d_in[6];
  const float* g2  = (const float*)d_in[7];
  const float* be2 = (const float*)d_in[8];
  const float* W4  = (const float*)d_in[9];
  const float* b4  = (const float*)d_in[10];
  float* out = (float*)d_out;

  char* ws = (char*)d_ws;
  unsigned short* h1     = (unsigned short*)(ws);              //  8 MB  [16384,256] bf16
  unsigned short* h2     = (unsigned short*)(ws + 8388608);    //  4 MB  [16384,128] bf16
  unsigned short* w1s    = (unsigned short*)(ws + 12582912);   //  2 MB  [256,4096] bf16
  unsigned short* w2s    = (unsigned short*)(ws + 14680064);   // 64 KB  [128,256] bf16
  float*          part1s = (float*)(ws + 14745600);            // 512 KB [256][512]
  float*          part1q = (float*)(ws + 15269888);            // 512 KB
  float*          part2s = (float*)(ws + 15794176);            // 128 KB [128][256]
  float*          part2q = (float*)(ws + 15925248);            // 128 KB
  float*          ab1    = (float*)(ws + 16056320);            // a1[256], c1[256]

  prep_sign_k<<<528, 256, 0, stream>>>(W1, w1s, W2, w2s);
  gemm1_k<<<256, 512, 0, stream>>>(x, w1s, b1, h1, part1s, part1q);
  params_k<256, 512><<<4, 64, 0, stream>>>(part1s, part1q, g1, be1, ab1);
  gemm2_k<<<256, 512, 0, stream>>>(h1, w2s, b2, ab1, h2, part2s, part2q);
  final_k<<<128, 128, 0, stream>>>(h2, part2s, part2q, g2, be2, W4, b4, out);
}